// Round 1
// 390.515 us; speedup vs baseline: 1.0368x; 1.0368x over previous
//
#include <hip/hip_runtime.h>
#include <math.h>

#define N_NODES 50000
#define N_EDGES 800000
#define N_GRAPHS 64
#define NEG_SLOPE 0.2f
#define SLOTS 64       // fixed bucket capacity; P(in-degree>64) ~ 1e-20 for Poisson(16)
#define FILL_BLOCKS 512

__device__ __forceinline__ float leaky(float x) {
    return x > 0.f ? x : NEG_SLOPE * x;
}

// ------- GEMM body: H = X @ W (f32); fused alpha: as_ = h@a_src, ad_ = h@a_dst -------
// Unchanged math from the 399us kernel; factored so it can be fused with fill.
template <int DOUT>
__device__ __forceinline__ void gemm_body(const float* __restrict__ X,
                                          const float* __restrict__ W,
                                          const float* __restrict__ a_src,
                                          const float* __restrict__ a_dst,
                                          float* __restrict__ H,
                                          float* __restrict__ as_,
                                          float* __restrict__ ad_, int N, int bid) {
    constexpr int DIN = 128;
    constexpr int CG = DOUT / 4;   // col groups of 4
    constexpr int RG = 256 / CG;   // row groups of 4
    constexpr int TILE_N = RG * 4;
    __shared__ __align__(16) float xs[TILE_N][DIN];

    const int n0 = bid * TILE_N;
    const int tid = threadIdx.x;

    for (int idx = tid; idx < TILE_N * (DIN / 4); idx += 256) {
        int r = idx / (DIN / 4);
        int q = idx % (DIN / 4);
        int n = n0 + r;
        float4 v = make_float4(0.f, 0.f, 0.f, 0.f);
        if (n < N) v = reinterpret_cast<const float4*>(X)[n * (DIN / 4) + q];
        reinterpret_cast<float4*>(&xs[r][0])[q] = v;
    }
    __syncthreads();

    const int cg = tid % CG;
    const int rg = tid / CG;
    const int c0 = cg * 4;
    const int r0 = rg * 4;

    float acc[4][4] = {};
    for (int k = 0; k < DIN; k += 4) {
        float4 w[4];
#pragma unroll
        for (int kk = 0; kk < 4; ++kk)
            w[kk] = *reinterpret_cast<const float4*>(&W[(k + kk) * DOUT + c0]);
#pragma unroll
        for (int i = 0; i < 4; ++i) {
            float4 xv = *reinterpret_cast<const float4*>(&xs[r0 + i][k]);
            const float xk[4] = {xv.x, xv.y, xv.z, xv.w};
#pragma unroll
            for (int kk = 0; kk < 4; ++kk) {
                acc[i][0] += xk[kk] * w[kk].x;
                acc[i][1] += xk[kk] * w[kk].y;
                acc[i][2] += xk[kk] * w[kk].z;
                acc[i][3] += xk[kk] * w[kk].w;
            }
        }
    }

    const float4 asv = *reinterpret_cast<const float4*>(&a_src[c0]);
    const float4 adv = *reinterpret_cast<const float4*>(&a_dst[c0]);
#pragma unroll
    for (int i = 0; i < 4; ++i) {
        const int n = n0 + r0 + i;
        if (n < N) {
            float4 o = make_float4(acc[i][0], acc[i][1], acc[i][2], acc[i][3]);
            *reinterpret_cast<float4*>(&H[(size_t)n * DOUT + c0]) = o;
        }
        float ps = acc[i][0] * asv.x + acc[i][1] * asv.y + acc[i][2] * asv.z + acc[i][3] * asv.w;
        float pd = acc[i][0] * adv.x + acc[i][1] * adv.y + acc[i][2] * adv.z + acc[i][3] * adv.w;
#pragma unroll
        for (int off = CG / 2; off; off >>= 1) {
            ps += __shfl_xor(ps, off, 64);
            pd += __shfl_xor(pd, off, 64);
        }
        if (cg == 0 && n < N) {
            as_[n] = ps;
            ad_[n] = pd;
        }
    }
}

template <int DOUT>
__global__ __launch_bounds__(256) void gemm_kernel(const float* __restrict__ X,
                                                   const float* __restrict__ W,
                                                   const float* __restrict__ a_src,
                                                   const float* __restrict__ a_dst,
                                                   float* __restrict__ H,
                                                   float* __restrict__ as_,
                                                   float* __restrict__ ad_, int N) {
    gemm_body<DOUT>(X, W, a_src, a_dst, H, as_, ad_, N, blockIdx.x);
}

// ------- fused layer-0 GEMM + adjacency fill (independent dataflow, overlap) -------
// Fill is latency/fabric-bound with ~0% VALU; gemm0 is VALU/LDS-bound. Co-residency
// hides the fill under the gemm. Fill blocks come FIRST in the grid so they start at t=0.
__global__ __launch_bounds__(256) void gemm0_fill_kernel(
    const float* __restrict__ X, const float* __restrict__ W,
    const float* __restrict__ a_src, const float* __restrict__ a_dst,
    float* __restrict__ H, float* __restrict__ as_, float* __restrict__ ad_, int N,
    const int* __restrict__ src, const int* __restrict__ dst,
    int* __restrict__ cursor, int* __restrict__ col, int E) {
    if (blockIdx.x < FILL_BLOCKS) {
        for (int e = blockIdx.x * 256 + threadIdx.x; e < E; e += FILL_BLOCKS * 256) {
            int d = dst[e];
            int p = atomicAdd(&cursor[d], 1);
            if (p < SLOTS) col[(d << 6) + p] = src[e];
        }
        return;
    }
    gemm_body<128>(X, W, a_src, a_dst, H, as_, ad_, N, blockIdx.x - FILL_BLOCKS);
}

// ------- fused softmax + gather per dst node (wave per node, no max pass) -------
// R11: unroll 4 edges per iteration -> 4 independent col/as_/H-row chains in flight
// per wave (2 KB of H per wave vs 1 KB), attacking the latency-bound 46%-HBM plateau.
template <int DOUT, bool RELU>
__global__ __launch_bounds__(256) void gather_kernel(const float* __restrict__ H,
                                                     const float* __restrict__ as_,
                                                     const float* __restrict__ ad_,
                                                     const int* __restrict__ cursor,
                                                     const int* __restrict__ col,
                                                     const float* __restrict__ bias,
                                                     float* __restrict__ OUT, int N) {
    constexpr int NCH4 = DOUT / 4;               // lanes per edge: 32 or 16
    constexpr int SUBS = 64 / NCH4;              // subgroups: 2 or 4
    const int node = blockIdx.x * 4 + (threadIdx.x >> 6);
    if (node >= N) return;
    const int l = threadIdx.x & 63;
    const int ch = l & (NCH4 - 1);
    const int sub = l / NCH4;

    const float adn = ad_[node];
    const float sl = leaky(as_[node] + adn);
    const int rs = node << 6;
    const int re = rs + min(cursor[node], SLOTS);

    const float4* __restrict__ H4 = reinterpret_cast<const float4*>(H);
    float4 acc = make_float4(0.f, 0.f, 0.f, 0.f);
    float dsum = 0.f;

    int i = rs + sub;
    // 4-edge unrolled main loop: all 4 col loads issue together, then 4 as_ loads,
    // then 4 H-row loads -> ~2x memory-level parallelism per wave.
    for (; i + 3 * SUBS < re; i += 4 * SUBS) {
        int s0 = col[i];
        int s1 = col[i + SUBS];
        int s2 = col[i + 2 * SUBS];
        int s3 = col[i + 3 * SUBS];
        float a0 = as_[s0];
        float a1 = as_[s1];
        float a2 = as_[s2];
        float a3 = as_[s3];
        float4 h0 = H4[(size_t)s0 * NCH4 + ch];
        float4 h1 = H4[(size_t)s1 * NCH4 + ch];
        float4 h2 = H4[(size_t)s2 * NCH4 + ch];
        float4 h3 = H4[(size_t)s3 * NCH4 + ch];
        float e0 = __expf(leaky(a0 + adn));
        float e1 = __expf(leaky(a1 + adn));
        float e2 = __expf(leaky(a2 + adn));
        float e3 = __expf(leaky(a3 + adn));
        acc.x += e0 * h0.x + e1 * h1.x + e2 * h2.x + e3 * h3.x;
        acc.y += e0 * h0.y + e1 * h1.y + e2 * h2.y + e3 * h3.y;
        acc.z += e0 * h0.z + e1 * h1.z + e2 * h2.z + e3 * h3.z;
        acc.w += e0 * h0.w + e1 * h1.w + e2 * h2.w + e3 * h3.w;
        dsum += (e0 + e1) + (e2 + e3);
    }
    // 2-edge tail (original R9 body)
    for (; i + SUBS < re; i += 2 * SUBS) {
        int s0 = col[i];
        int s1 = col[i + SUBS];
        float e0 = __expf(leaky(as_[s0] + adn));
        float e1 = __expf(leaky(as_[s1] + adn));
        float4 h0 = H4[(size_t)s0 * NCH4 + ch];
        float4 h1 = H4[(size_t)s1 * NCH4 + ch];
        acc.x += e0 * h0.x + e1 * h1.x;
        acc.y += e0 * h0.y + e1 * h1.y;
        acc.z += e0 * h0.z + e1 * h1.z;
        acc.w += e0 * h0.w + e1 * h1.w;
        dsum += e0 + e1;
    }
    if (i < re) {
        int s0 = col[i];
        float e0 = __expf(leaky(as_[s0] + adn));
        float4 h0 = H4[(size_t)s0 * NCH4 + ch];
        acc.x += e0 * h0.x;
        acc.y += e0 * h0.y;
        acc.z += e0 * h0.z;
        acc.w += e0 * h0.w;
        dsum += e0;
    }

    // dsum identical across a subgroup's NCH4 lanes; combine subgroups only
#pragma unroll
    for (int off = 32; off >= NCH4; off >>= 1)
        dsum += __shfl_xor(dsum, off, 64);
#pragma unroll
    for (int off = 32; off >= NCH4; off >>= 1) {
        acc.x += __shfl_down(acc.x, off, 64);
        acc.y += __shfl_down(acc.y, off, 64);
        acc.z += __shfl_down(acc.z, off, 64);
        acc.w += __shfl_down(acc.w, off, 64);
    }

    if (l < NCH4) {
        const float e_self = __expf(sl);
        float4 h = H4[(size_t)node * NCH4 + ch];
        acc.x += e_self * h.x;
        acc.y += e_self * h.y;
        acc.z += e_self * h.z;
        acc.w += e_self * h.w;
        const float inv = 1.f / (dsum + e_self);
        const float4 b4 = reinterpret_cast<const float4*>(bias)[ch];
        float4 r;
        r.x = acc.x * inv + b4.x;
        r.y = acc.y * inv + b4.y;
        r.z = acc.z * inv + b4.z;
        r.w = acc.w * inv + b4.w;
        if (RELU) {
            r.x = fmaxf(r.x, 0.f);
            r.y = fmaxf(r.y, 0.f);
            r.z = fmaxf(r.z, 0.f);
            r.w = fmaxf(r.w, 0.f);
        }
        reinterpret_cast<float4*>(OUT)[(size_t)node * NCH4 + ch] = r;
    }
}

// ---------------- global add pool over sorted batch ----------------
__global__ __launch_bounds__(256) void pool_kernel(const float* __restrict__ H2,
                                                   const int* __restrict__ batch,
                                                   float* __restrict__ out, int N) {
    const int wv = threadIdx.x >> 6;
    const int c = threadIdx.x & 63;
    const int n0 = blockIdx.x * 128 + wv * 32;
    if (n0 >= N) return;
    const int n1 = min(n0 + 32, N);
    float acc = 0.f;
    int cur = batch[n0];
    for (int n = n0; n < n1; ++n) {
        int g = batch[n];
        if (g != cur) {
            atomicAdd(&out[cur * 64 + c], acc);
            acc = 0.f;
            cur = g;
        }
        acc += H2[n * 64 + c];
    }
    atomicAdd(&out[cur * 64 + c], acc);
}

extern "C" void kernel_launch(void* const* d_in, const int* in_sizes, int n_in,
                              void* d_out, int out_size, void* d_ws, size_t ws_size,
                              hipStream_t stream) {
    const float* x = (const float*)d_in[0];
    const int* edge_index = (const int*)d_in[1];
    const int* batch = (const int*)d_in[2];
    const float* W0 = (const float*)d_in[3];
    const float* as0 = (const float*)d_in[4];
    const float* ad0 = (const float*)d_in[5];
    const float* b0 = (const float*)d_in[6];
    const float* W1 = (const float*)d_in[7];
    const float* as1 = (const float*)d_in[8];
    const float* ad1 = (const float*)d_in[9];
    const float* b1 = (const float*)d_in[10];
    const float* W2 = (const float*)d_in[11];
    const float* as2 = (const float*)d_in[12];
    const float* ad2 = (const float*)d_in[13];
    const float* b2 = (const float*)d_in[14];

    const int* e_src = edge_index;            // row 0
    const int* e_dst = edge_index + N_EDGES;  // row 1

    // workspace layout (floats)
    float* B0 = (float*)d_ws;                 // 50000*128
    float* H = B0 + N_NODES * 128;            // 50000*128
    float* as_ = H + N_NODES * 128;           // 50000
    float* ad_ = as_ + N_NODES;               // 50000
    int* cursor = (int*)(ad_ + N_NODES);      // 50000 (counts after fill)
    int* col = cursor + N_NODES;              // 50000*64 bucketed adjacency

    hipMemsetAsync(cursor, 0, N_NODES * sizeof(int), stream);

    const int NODE_BLOCKS = (N_NODES + 3) / 4;
    const int GEMM128_BLOCKS = (N_NODES + 31) / 32;

    // ---- layer 0 gemm fused with adjacency fill (independent -> overlap) ----
    gemm0_fill_kernel<<<FILL_BLOCKS + GEMM128_BLOCKS, 256, 0, stream>>>(
        x, W0, as0, ad0, H, as_, ad_, N_NODES, e_src, e_dst, cursor, col, N_EDGES);
    gather_kernel<128, true><<<NODE_BLOCKS, 256, 0, stream>>>(H, as_, ad_, cursor, col, b0, B0, N_NODES);

    // ---- layer 1: B0 -> B0 (relu) ----
    gemm_kernel<128><<<GEMM128_BLOCKS, 256, 0, stream>>>(B0, W1, as1, ad1, H, as_, ad_, N_NODES);
    gather_kernel<128, true><<<NODE_BLOCKS, 256, 0, stream>>>(H, as_, ad_, cursor, col, b1, B0, N_NODES);

    // ---- layer 2: B0 -> B0 (64-wide, no relu) ----
    gemm_kernel<64><<<(N_NODES + 63) / 64, 256, 0, stream>>>(B0, W2, as2, ad2, H, as_, ad_, N_NODES);
    gather_kernel<64, false><<<NODE_BLOCKS, 256, 0, stream>>>(H, as_, ad_, cursor, col, b2, B0, N_NODES);

    // ---- pool ----
    hipMemsetAsync(d_out, 0, (size_t)out_size * sizeof(float), stream);
    pool_kernel<<<(N_NODES + 127) / 128, 256, 0, stream>>>(B0, batch, (float*)d_out, N_NODES);
}

// Round 2
// 384.215 us; speedup vs baseline: 1.0538x; 1.0164x over previous
//
#include <hip/hip_runtime.h>
#include <math.h>

#define N_NODES 50000
#define N_EDGES 800000
#define N_GRAPHS 64
#define NEG_SLOPE 0.2f
#define SLOTS 64       // fixed bucket capacity; P(in-degree>64) ~ 1e-20 for Poisson(16)
#define FILL_BLOCKS 512

__device__ __forceinline__ float leaky(float x) {
    return x > 0.f ? x : NEG_SLOPE * x;
}

// ------- GEMM body: H = X @ W (f32); fused alpha: as_ = h@a_src, ad_ = h@a_dst -------
template <int DOUT>
__device__ __forceinline__ void gemm_body(const float* __restrict__ X,
                                          const float* __restrict__ W,
                                          const float* __restrict__ a_src,
                                          const float* __restrict__ a_dst,
                                          float* __restrict__ H,
                                          float* __restrict__ as_,
                                          float* __restrict__ ad_, int N, int bid) {
    constexpr int DIN = 128;
    constexpr int CG = DOUT / 4;   // col groups of 4
    constexpr int RG = 256 / CG;   // row groups of 4
    constexpr int TILE_N = RG * 4;
    __shared__ __align__(16) float xs[TILE_N][DIN];

    const int n0 = bid * TILE_N;
    const int tid = threadIdx.x;

    for (int idx = tid; idx < TILE_N * (DIN / 4); idx += 256) {
        int r = idx / (DIN / 4);
        int q = idx % (DIN / 4);
        int n = n0 + r;
        float4 v = make_float4(0.f, 0.f, 0.f, 0.f);
        if (n < N) v = reinterpret_cast<const float4*>(X)[n * (DIN / 4) + q];
        reinterpret_cast<float4*>(&xs[r][0])[q] = v;
    }
    __syncthreads();

    const int cg = tid % CG;
    const int rg = tid / CG;
    const int c0 = cg * 4;
    const int r0 = rg * 4;

    float acc[4][4] = {};
    for (int k = 0; k < DIN; k += 4) {
        float4 w[4];
#pragma unroll
        for (int kk = 0; kk < 4; ++kk)
            w[kk] = *reinterpret_cast<const float4*>(&W[(k + kk) * DOUT + c0]);
#pragma unroll
        for (int i = 0; i < 4; ++i) {
            float4 xv = *reinterpret_cast<const float4*>(&xs[r0 + i][k]);
            const float xk[4] = {xv.x, xv.y, xv.z, xv.w};
#pragma unroll
            for (int kk = 0; kk < 4; ++kk) {
                acc[i][0] += xk[kk] * w[kk].x;
                acc[i][1] += xk[kk] * w[kk].y;
                acc[i][2] += xk[kk] * w[kk].z;
                acc[i][3] += xk[kk] * w[kk].w;
            }
        }
    }

    const float4 asv = *reinterpret_cast<const float4*>(&a_src[c0]);
    const float4 adv = *reinterpret_cast<const float4*>(&a_dst[c0]);
#pragma unroll
    for (int i = 0; i < 4; ++i) {
        const int n = n0 + r0 + i;
        if (n < N) {
            float4 o = make_float4(acc[i][0], acc[i][1], acc[i][2], acc[i][3]);
            *reinterpret_cast<float4*>(&H[(size_t)n * DOUT + c0]) = o;
        }
        float ps = acc[i][0] * asv.x + acc[i][1] * asv.y + acc[i][2] * asv.z + acc[i][3] * asv.w;
        float pd = acc[i][0] * adv.x + acc[i][1] * adv.y + acc[i][2] * adv.z + acc[i][3] * adv.w;
#pragma unroll
        for (int off = CG / 2; off; off >>= 1) {
            ps += __shfl_xor(ps, off, 64);
            pd += __shfl_xor(pd, off, 64);
        }
        if (cg == 0 && n < N) {
            as_[n] = ps;
            ad_[n] = pd;
        }
    }
}

template <int DOUT>
__global__ __launch_bounds__(256) void gemm_kernel(const float* __restrict__ X,
                                                   const float* __restrict__ W,
                                                   const float* __restrict__ a_src,
                                                   const float* __restrict__ a_dst,
                                                   float* __restrict__ H,
                                                   float* __restrict__ as_,
                                                   float* __restrict__ ad_, int N) {
    gemm_body<DOUT>(X, W, a_src, a_dst, H, as_, ad_, N, blockIdx.x);
}

// ------- fused layer-0 GEMM + adjacency fill (independent dataflow, overlap) -------
// R12: fill is latency-chain-bound (dst load -> atomicAdd round-trip -> scattered
// store). At 512 blocks each thread walks ~6 chains SEQUENTIALLY; unroll x4 makes
// them independent -> 524K concurrent chains, same MLP as the old 2048-block fill.
// col entries are ushort (N<65536): bucket = 128B = 2 cache lines, halving the
// scattered-store line amplification (WRITE_SIZE).
__global__ __launch_bounds__(256) void gemm0_fill_kernel(
    const float* __restrict__ X, const float* __restrict__ W,
    const float* __restrict__ a_src, const float* __restrict__ a_dst,
    float* __restrict__ H, float* __restrict__ as_, float* __restrict__ ad_, int N,
    const int* __restrict__ src, const int* __restrict__ dst,
    int* __restrict__ cursor, unsigned short* __restrict__ col, int E) {
    if (blockIdx.x < FILL_BLOCKS) {
        const int stride = FILL_BLOCKS * 256;
        int e = blockIdx.x * 256 + threadIdx.x;
        for (; e + 3 * stride < E; e += 4 * stride) {
            int d0 = dst[e];
            int d1 = dst[e + stride];
            int d2 = dst[e + 2 * stride];
            int d3 = dst[e + 3 * stride];
            int s0 = src[e];
            int s1 = src[e + stride];
            int s2 = src[e + 2 * stride];
            int s3 = src[e + 3 * stride];
            int p0 = atomicAdd(&cursor[d0], 1);
            int p1 = atomicAdd(&cursor[d1], 1);
            int p2 = atomicAdd(&cursor[d2], 1);
            int p3 = atomicAdd(&cursor[d3], 1);
            if (p0 < SLOTS) col[(d0 << 6) + p0] = (unsigned short)s0;
            if (p1 < SLOTS) col[(d1 << 6) + p1] = (unsigned short)s1;
            if (p2 < SLOTS) col[(d2 << 6) + p2] = (unsigned short)s2;
            if (p3 < SLOTS) col[(d3 << 6) + p3] = (unsigned short)s3;
        }
        for (; e < E; e += stride) {
            int d = dst[e];
            int p = atomicAdd(&cursor[d], 1);
            if (p < SLOTS) col[(d << 6) + p] = (unsigned short)src[e];
        }
        return;
    }
    gemm_body<128>(X, W, a_src, a_dst, H, as_, ad_, N, blockIdx.x - FILL_BLOCKS);
}

// ------- fused softmax + gather per dst node (wave per node, no max pass) -------
// R12: 8/4/2/1 unroll ladder -> up to 8 independent col/as_/H-row chains in flight.
template <int DOUT, bool RELU>
__global__ __launch_bounds__(256) void gather_kernel(const float* __restrict__ H,
                                                     const float* __restrict__ as_,
                                                     const float* __restrict__ ad_,
                                                     const int* __restrict__ cursor,
                                                     const unsigned short* __restrict__ col,
                                                     const float* __restrict__ bias,
                                                     float* __restrict__ OUT, int N) {
    constexpr int NCH4 = DOUT / 4;               // lanes per edge: 32 or 16
    constexpr int SUBS = 64 / NCH4;              // subgroups: 2 or 4
    const int node = blockIdx.x * 4 + (threadIdx.x >> 6);
    if (node >= N) return;
    const int l = threadIdx.x & 63;
    const int ch = l & (NCH4 - 1);
    const int sub = l / NCH4;

    const float adn = ad_[node];
    const float sl = leaky(as_[node] + adn);
    const int rs = node << 6;
    const int re = rs + min(cursor[node], SLOTS);

    const float4* __restrict__ H4 = reinterpret_cast<const float4*>(H);
    float4 acc = make_float4(0.f, 0.f, 0.f, 0.f);
    float dsum = 0.f;

    int i = rs + sub;
    // 8-edge unrolled main loop (consumes 8*SUBS edges/iter)
    for (; i + 7 * SUBS < re; i += 8 * SUBS) {
        int s[8];
        float a[8];
        float4 h[8];
#pragma unroll
        for (int u = 0; u < 8; ++u) s[u] = col[i + u * SUBS];
#pragma unroll
        for (int u = 0; u < 8; ++u) a[u] = as_[s[u]];
#pragma unroll
        for (int u = 0; u < 8; ++u) h[u] = H4[(size_t)s[u] * NCH4 + ch];
#pragma unroll
        for (int u = 0; u < 8; ++u) {
            float ee = __expf(leaky(a[u] + adn));
            acc.x += ee * h[u].x;
            acc.y += ee * h[u].y;
            acc.z += ee * h[u].z;
            acc.w += ee * h[u].w;
            dsum += ee;
        }
    }
    // 4-edge tail
    for (; i + 3 * SUBS < re; i += 4 * SUBS) {
        int s[4];
        float a[4];
        float4 h[4];
#pragma unroll
        for (int u = 0; u < 4; ++u) s[u] = col[i + u * SUBS];
#pragma unroll
        for (int u = 0; u < 4; ++u) a[u] = as_[s[u]];
#pragma unroll
        for (int u = 0; u < 4; ++u) h[u] = H4[(size_t)s[u] * NCH4 + ch];
#pragma unroll
        for (int u = 0; u < 4; ++u) {
            float ee = __expf(leaky(a[u] + adn));
            acc.x += ee * h[u].x;
            acc.y += ee * h[u].y;
            acc.z += ee * h[u].z;
            acc.w += ee * h[u].w;
            dsum += ee;
        }
    }
    // 2-edge tail
    for (; i + SUBS < re; i += 2 * SUBS) {
        int s0 = col[i];
        int s1 = col[i + SUBS];
        float e0 = __expf(leaky(as_[s0] + adn));
        float e1 = __expf(leaky(as_[s1] + adn));
        float4 h0 = H4[(size_t)s0 * NCH4 + ch];
        float4 h1 = H4[(size_t)s1 * NCH4 + ch];
        acc.x += e0 * h0.x + e1 * h1.x;
        acc.y += e0 * h0.y + e1 * h1.y;
        acc.z += e0 * h0.z + e1 * h1.z;
        acc.w += e0 * h0.w + e1 * h1.w;
        dsum += e0 + e1;
    }
    if (i < re) {
        int s0 = col[i];
        float e0 = __expf(leaky(as_[s0] + adn));
        float4 h0 = H4[(size_t)s0 * NCH4 + ch];
        acc.x += e0 * h0.x;
        acc.y += e0 * h0.y;
        acc.z += e0 * h0.z;
        acc.w += e0 * h0.w;
        dsum += e0;
    }

    // dsum identical across a subgroup's NCH4 lanes; combine subgroups only
#pragma unroll
    for (int off = 32; off >= NCH4; off >>= 1)
        dsum += __shfl_xor(dsum, off, 64);
#pragma unroll
    for (int off = 32; off >= NCH4; off >>= 1) {
        acc.x += __shfl_down(acc.x, off, 64);
        acc.y += __shfl_down(acc.y, off, 64);
        acc.z += __shfl_down(acc.z, off, 64);
        acc.w += __shfl_down(acc.w, off, 64);
    }

    if (l < NCH4) {
        const float e_self = __expf(sl);
        float4 h = H4[(size_t)node * NCH4 + ch];
        acc.x += e_self * h.x;
        acc.y += e_self * h.y;
        acc.z += e_self * h.z;
        acc.w += e_self * h.w;
        const float inv = 1.f / (dsum + e_self);
        const float4 b4 = reinterpret_cast<const float4*>(bias)[ch];
        float4 r;
        r.x = acc.x * inv + b4.x;
        r.y = acc.y * inv + b4.y;
        r.z = acc.z * inv + b4.z;
        r.w = acc.w * inv + b4.w;
        if (RELU) {
            r.x = fmaxf(r.x, 0.f);
            r.y = fmaxf(r.y, 0.f);
            r.z = fmaxf(r.z, 0.f);
            r.w = fmaxf(r.w, 0.f);
        }
        reinterpret_cast<float4*>(OUT)[(size_t)node * NCH4 + ch] = r;
    }
}

// ---------------- global add pool over sorted batch ----------------
__global__ __launch_bounds__(256) void pool_kernel(const float* __restrict__ H2,
                                                   const int* __restrict__ batch,
                                                   float* __restrict__ out, int N) {
    const int wv = threadIdx.x >> 6;
    const int c = threadIdx.x & 63;
    const int n0 = blockIdx.x * 128 + wv * 32;
    if (n0 >= N) return;
    const int n1 = min(n0 + 32, N);
    float acc = 0.f;
    int cur = batch[n0];
    for (int n = n0; n < n1; ++n) {
        int g = batch[n];
        if (g != cur) {
            atomicAdd(&out[cur * 64 + c], acc);
            acc = 0.f;
            cur = g;
        }
        acc += H2[n * 64 + c];
    }
    atomicAdd(&out[cur * 64 + c], acc);
}

extern "C" void kernel_launch(void* const* d_in, const int* in_sizes, int n_in,
                              void* d_out, int out_size, void* d_ws, size_t ws_size,
                              hipStream_t stream) {
    const float* x = (const float*)d_in[0];
    const int* edge_index = (const int*)d_in[1];
    const int* batch = (const int*)d_in[2];
    const float* W0 = (const float*)d_in[3];
    const float* as0 = (const float*)d_in[4];
    const float* ad0 = (const float*)d_in[5];
    const float* b0 = (const float*)d_in[6];
    const float* W1 = (const float*)d_in[7];
    const float* as1 = (const float*)d_in[8];
    const float* ad1 = (const float*)d_in[9];
    const float* b1 = (const float*)d_in[10];
    const float* W2 = (const float*)d_in[11];
    const float* as2 = (const float*)d_in[12];
    const float* ad2 = (const float*)d_in[13];
    const float* b2 = (const float*)d_in[14];

    const int* e_src = edge_index;            // row 0
    const int* e_dst = edge_index + N_EDGES;  // row 1

    // workspace layout (floats)
    float* B0 = (float*)d_ws;                 // 50000*128
    float* H = B0 + N_NODES * 128;            // 50000*128
    float* as_ = H + N_NODES * 128;           // 50000
    float* ad_ = as_ + N_NODES;               // 50000
    int* cursor = (int*)(ad_ + N_NODES);      // 50000 (counts after fill)
    unsigned short* col = (unsigned short*)(cursor + N_NODES);  // 50000*64 ushort buckets

    hipMemsetAsync(cursor, 0, N_NODES * sizeof(int), stream);

    const int NODE_BLOCKS = (N_NODES + 3) / 4;
    const int GEMM128_BLOCKS = (N_NODES + 31) / 32;

    // ---- layer 0 gemm fused with adjacency fill (independent -> overlap) ----
    gemm0_fill_kernel<<<FILL_BLOCKS + GEMM128_BLOCKS, 256, 0, stream>>>(
        x, W0, as0, ad0, H, as_, ad_, N_NODES, e_src, e_dst, cursor, col, N_EDGES);
    gather_kernel<128, true><<<NODE_BLOCKS, 256, 0, stream>>>(H, as_, ad_, cursor, col, b0, B0, N_NODES);

    // ---- layer 1: B0 -> B0 (relu) ----
    gemm_kernel<128><<<GEMM128_BLOCKS, 256, 0, stream>>>(B0, W1, as1, ad1, H, as_, ad_, N_NODES);
    gather_kernel<128, true><<<NODE_BLOCKS, 256, 0, stream>>>(H, as_, ad_, cursor, col, b1, B0, N_NODES);

    // ---- layer 2: B0 -> B0 (64-wide, no relu) ----
    gemm_kernel<64><<<(N_NODES + 63) / 64, 256, 0, stream>>>(B0, W2, as2, ad2, H, as_, ad_, N_NODES);
    gather_kernel<64, false><<<NODE_BLOCKS, 256, 0, stream>>>(H, as_, ad_, cursor, col, b2, B0, N_NODES);

    // ---- pool ----
    hipMemsetAsync(d_out, 0, (size_t)out_size * sizeof(float), stream);
    pool_kernel<<<(N_NODES + 127) / 128, 256, 0, stream>>>(B0, batch, (float*)d_out, N_NODES);
}

// Round 3
// 362.787 us; speedup vs baseline: 1.1160x; 1.0591x over previous
//
#include <hip/hip_runtime.h>
#include <math.h>

#define N_NODES 50000
#define N_EDGES 800000
#define N_GRAPHS 64
#define NEG_SLOPE 0.2f
#define SLOTS 64        // bucket capacity; P(in-degree>64) ~ 1e-20 for Poisson(16)

// ---- multisplit fill parameters ----
#define BIN_NODES 256                   // nodes per dst-range bin
#define NBINS 196                       // ceil(50000/256)
#define CAP 6144                        // u32 slots per bin (mean 4082, sigma ~64)
#define P1_BLOCKS 192                   // pass-1 blocks fused ahead of gemm0
#define BATCH 2048                      // edges per block-batch (8 per thread)

__device__ __forceinline__ float leaky(float x) {
    return x > 0.f ? x : NEG_SLOPE * x;
}

// ------- GEMM body: H = X @ W (f32); fused alpha: as_ = h@a_src, ad_ = h@a_dst -------
// xsmem: caller-provided LDS (TILE_N*128 floats) so the fused kernel can union it
// with pass-1's staging memory.
template <int DOUT>
__device__ __forceinline__ void gemm_body(const float* __restrict__ X,
                                          const float* __restrict__ W,
                                          const float* __restrict__ a_src,
                                          const float* __restrict__ a_dst,
                                          float* __restrict__ H,
                                          float* __restrict__ as_,
                                          float* __restrict__ ad_, int N, int bid,
                                          float* xsmem) {
    constexpr int DIN = 128;
    constexpr int CG = DOUT / 4;   // col groups of 4
    constexpr int RG = 256 / CG;   // row groups of 4
    constexpr int TILE_N = RG * 4;
    float (*xs)[DIN] = reinterpret_cast<float (*)[DIN]>(xsmem);

    const int n0 = bid * TILE_N;
    const int tid = threadIdx.x;

    for (int idx = tid; idx < TILE_N * (DIN / 4); idx += 256) {
        int r = idx / (DIN / 4);
        int q = idx % (DIN / 4);
        int n = n0 + r;
        float4 v = make_float4(0.f, 0.f, 0.f, 0.f);
        if (n < N) v = reinterpret_cast<const float4*>(X)[n * (DIN / 4) + q];
        reinterpret_cast<float4*>(&xs[r][0])[q] = v;
    }
    __syncthreads();

    const int cg = tid % CG;
    const int rg = tid / CG;
    const int c0 = cg * 4;
    const int r0 = rg * 4;

    float acc[4][4] = {};
    for (int k = 0; k < DIN; k += 4) {
        float4 w[4];
#pragma unroll
        for (int kk = 0; kk < 4; ++kk)
            w[kk] = *reinterpret_cast<const float4*>(&W[(k + kk) * DOUT + c0]);
#pragma unroll
        for (int i = 0; i < 4; ++i) {
            float4 xv = *reinterpret_cast<const float4*>(&xs[r0 + i][k]);
            const float xk[4] = {xv.x, xv.y, xv.z, xv.w};
#pragma unroll
            for (int kk = 0; kk < 4; ++kk) {
                acc[i][0] += xk[kk] * w[kk].x;
                acc[i][1] += xk[kk] * w[kk].y;
                acc[i][2] += xk[kk] * w[kk].z;
                acc[i][3] += xk[kk] * w[kk].w;
            }
        }
    }

    const float4 asv = *reinterpret_cast<const float4*>(&a_src[c0]);
    const float4 adv = *reinterpret_cast<const float4*>(&a_dst[c0]);
#pragma unroll
    for (int i = 0; i < 4; ++i) {
        const int n = n0 + r0 + i;
        if (n < N) {
            float4 o = make_float4(acc[i][0], acc[i][1], acc[i][2], acc[i][3]);
            *reinterpret_cast<float4*>(&H[(size_t)n * DOUT + c0]) = o;
        }
        float ps = acc[i][0] * asv.x + acc[i][1] * asv.y + acc[i][2] * asv.z + acc[i][3] * asv.w;
        float pd = acc[i][0] * adv.x + acc[i][1] * adv.y + acc[i][2] * adv.z + acc[i][3] * adv.w;
#pragma unroll
        for (int off = CG / 2; off; off >>= 1) {
            ps += __shfl_xor(ps, off, 64);
            pd += __shfl_xor(pd, off, 64);
        }
        if (cg == 0 && n < N) {
            as_[n] = ps;
            ad_[n] = pd;
        }
    }
}

template <int DOUT>
__global__ __launch_bounds__(256) void gemm_kernel(const float* __restrict__ X,
                                                   const float* __restrict__ W,
                                                   const float* __restrict__ a_src,
                                                   const float* __restrict__ a_dst,
                                                   float* __restrict__ H,
                                                   float* __restrict__ as_,
                                                   float* __restrict__ ad_, int N) {
    constexpr int TILE_N = (256 / (DOUT / 4)) * 4;
    __shared__ __align__(16) float xs[TILE_N][128];
    gemm_body<DOUT>(X, W, a_src, a_dst, H, as_, ad_, N, blockIdx.x, &xs[0][0]);
}

// ------- pass 1: multisplit edges into 196 dst-range bins (packed u32 = d<<16|s) -------
// Converts 800K random-sector stores + 800K global atomics into coalesced ~21-edge
// runs + ~38K global atomics. Random-sector fabric load (R2's fill bottleneck) gone.
struct P1Smem {
    unsigned int stage[BATCH];
    int hist[NBINS];
    int off[NBINS];
    unsigned int gbase[NBINS];
    int total;
};

__device__ __forceinline__ void fill_pass1(const int* __restrict__ src,
                                           const int* __restrict__ dst,
                                           unsigned int* __restrict__ bin_cursor,
                                           unsigned int* __restrict__ bin_buf,
                                           int E, int bid, void* smem_raw) {
    P1Smem& S = *reinterpret_cast<P1Smem*>(smem_raw);
    const int tid = threadIdx.x;
    const int nbatch = (E + BATCH - 1) / BATCH;
    for (int b = bid; b < nbatch; b += P1_BLOCKS) {
        __syncthreads();  // protect stage/hist reuse across batches
        for (int i = tid; i < NBINS; i += 256) S.hist[i] = 0;
        const int e0 = b * BATCH;
        unsigned int pk[8];
        int rk[8];
        bool ok[8];
#pragma unroll
        for (int k = 0; k < 8; ++k) {
            int e = e0 + tid + k * 256;
            ok[k] = (e < E);
            int d = ok[k] ? dst[e] : 0;
            int s = ok[k] ? src[e] : 0;
            pk[k] = ((unsigned)d << 16) | (unsigned)s;
            rk[k] = 0;
        }
        __syncthreads();
#pragma unroll
        for (int k = 0; k < 8; ++k)
            if (ok[k]) rk[k] = atomicAdd(&S.hist[pk[k] >> 24], 1);
        __syncthreads();
        if (tid == 0) {
            int run = 0;
            for (int i = 0; i < NBINS; ++i) {
                S.off[i] = run;
                run += S.hist[i];
            }
            S.total = run;
        }
        __syncthreads();
        if (tid < NBINS && S.hist[tid] > 0)
            S.gbase[tid] = atomicAdd(&bin_cursor[tid], (unsigned)S.hist[tid]);
#pragma unroll
        for (int k = 0; k < 8; ++k)
            if (ok[k]) S.stage[S.off[pk[k] >> 24] + rk[k]] = pk[k];
        __syncthreads();
        const int tot = S.total;
        for (int i = tid; i < tot; i += 256) {
            unsigned int v = S.stage[i];
            int bn = v >> 24;
            unsigned int p = S.gbase[bn] + (unsigned)(i - S.off[bn]);
            if (p < CAP) bin_buf[(size_t)bn * CAP + p] = v;
        }
    }
}

// ------- fused layer-0 GEMM + pass-1 (independent dataflow -> overlap) -------
__global__ __launch_bounds__(256) void gemm0_fill_kernel(
    const float* __restrict__ X, const float* __restrict__ W,
    const float* __restrict__ a_src, const float* __restrict__ a_dst,
    float* __restrict__ H, float* __restrict__ as_, float* __restrict__ ad_, int N,
    const int* __restrict__ src, const int* __restrict__ dst,
    unsigned int* __restrict__ bin_cursor, unsigned int* __restrict__ bin_buf, int E) {
    __shared__ __align__(16) unsigned char smem[16384];  // union: P1Smem (10.5KB) / xs (16KB)
    if (blockIdx.x < P1_BLOCKS) {
        fill_pass1(src, dst, bin_cursor, bin_buf, E, blockIdx.x, smem);
        return;
    }
    gemm_body<128>(X, W, a_src, a_dst, H, as_, ad_, N, blockIdx.x - P1_BLOCKS,
                   reinterpret_cast<float*>(smem));
}

// ------- pass 2: per-bin bucket build in LDS, coalesced writeback -------
// One block per 256-node bin: LDS atomics (cheap) replace global atomics; the
// 64KB bucket block + cursors stream out fully coalesced. Also writes cursor[]
// directly (drops the 200KB cursor memset).
__global__ __launch_bounds__(256) void fill_pass2(const unsigned int* __restrict__ bin_cursor,
                                                  const unsigned int* __restrict__ bin_buf,
                                                  int* __restrict__ cursor,
                                                  unsigned short* __restrict__ col, int N) {
    __shared__ unsigned short bk[BIN_NODES][SLOTS];  // 32KB
    __shared__ int cnt[BIN_NODES];                   // 1KB
    const int b = blockIdx.x;
    const int tid = threadIdx.x;
    const int base = b * BIN_NODES;
    const int nn = min(BIN_NODES, N - base);
    if (nn <= 0) return;
    cnt[tid] = 0;
    __syncthreads();
    const int ec = min((int)bin_cursor[b], CAP);
    for (int i = tid; i < ec; i += 256) {
        unsigned int v = bin_buf[(size_t)b * CAP + i];
        int d = (int)(v >> 16) - base;  // in [0, BIN_NODES)
        int p = atomicAdd(&cnt[d], 1);
        if (p < SLOTS) bk[d][p] = (unsigned short)(v & 0xFFFFu);
    }
    __syncthreads();
    unsigned int* col32 = reinterpret_cast<unsigned int*>(col);
    const unsigned int* lds32 = reinterpret_cast<const unsigned int*>(&bk[0][0]);
    const int words = nn * (SLOTS / 2);
    for (int i = tid; i < words; i += 256)
        col32[(size_t)base * (SLOTS / 2) + i] = lds32[i];
    if (tid < nn) cursor[base + tid] = cnt[tid];
}

// ------- fused softmax + gather per dst node (wave per node, no max pass) -------
template <int DOUT, bool RELU>
__global__ __launch_bounds__(256) void gather_kernel(const float* __restrict__ H,
                                                     const float* __restrict__ as_,
                                                     const float* __restrict__ ad_,
                                                     const int* __restrict__ cursor,
                                                     const unsigned short* __restrict__ col,
                                                     const float* __restrict__ bias,
                                                     float* __restrict__ OUT, int N) {
    constexpr int NCH4 = DOUT / 4;               // lanes per edge: 32 or 16
    constexpr int SUBS = 64 / NCH4;              // subgroups: 2 or 4
    const int node = blockIdx.x * 4 + (threadIdx.x >> 6);
    if (node >= N) return;
    const int l = threadIdx.x & 63;
    const int ch = l & (NCH4 - 1);
    const int sub = l / NCH4;

    const float adn = ad_[node];
    const float sl = leaky(as_[node] + adn);
    const int rs = node << 6;
    const int re = rs + min(cursor[node], SLOTS);

    const float4* __restrict__ H4 = reinterpret_cast<const float4*>(H);
    float4 acc = make_float4(0.f, 0.f, 0.f, 0.f);
    float dsum = 0.f;

    int i = rs + sub;
    for (; i + 7 * SUBS < re; i += 8 * SUBS) {
        int s[8];
        float a[8];
        float4 h[8];
#pragma unroll
        for (int u = 0; u < 8; ++u) s[u] = col[i + u * SUBS];
#pragma unroll
        for (int u = 0; u < 8; ++u) a[u] = as_[s[u]];
#pragma unroll
        for (int u = 0; u < 8; ++u) h[u] = H4[(size_t)s[u] * NCH4 + ch];
#pragma unroll
        for (int u = 0; u < 8; ++u) {
            float ee = __expf(leaky(a[u] + adn));
            acc.x += ee * h[u].x;
            acc.y += ee * h[u].y;
            acc.z += ee * h[u].z;
            acc.w += ee * h[u].w;
            dsum += ee;
        }
    }
    for (; i + 3 * SUBS < re; i += 4 * SUBS) {
        int s[4];
        float a[4];
        float4 h[4];
#pragma unroll
        for (int u = 0; u < 4; ++u) s[u] = col[i + u * SUBS];
#pragma unroll
        for (int u = 0; u < 4; ++u) a[u] = as_[s[u]];
#pragma unroll
        for (int u = 0; u < 4; ++u) h[u] = H4[(size_t)s[u] * NCH4 + ch];
#pragma unroll
        for (int u = 0; u < 4; ++u) {
            float ee = __expf(leaky(a[u] + adn));
            acc.x += ee * h[u].x;
            acc.y += ee * h[u].y;
            acc.z += ee * h[u].z;
            acc.w += ee * h[u].w;
            dsum += ee;
        }
    }
    for (; i + SUBS < re; i += 2 * SUBS) {
        int s0 = col[i];
        int s1 = col[i + SUBS];
        float e0 = __expf(leaky(as_[s0] + adn));
        float e1 = __expf(leaky(as_[s1] + adn));
        float4 h0 = H4[(size_t)s0 * NCH4 + ch];
        float4 h1 = H4[(size_t)s1 * NCH4 + ch];
        acc.x += e0 * h0.x + e1 * h1.x;
        acc.y += e0 * h0.y + e1 * h1.y;
        acc.z += e0 * h0.z + e1 * h1.z;
        acc.w += e0 * h0.w + e1 * h1.w;
        dsum += e0 + e1;
    }
    if (i < re) {
        int s0 = col[i];
        float e0 = __expf(leaky(as_[s0] + adn));
        float4 h0 = H4[(size_t)s0 * NCH4 + ch];
        acc.x += e0 * h0.x;
        acc.y += e0 * h0.y;
        acc.z += e0 * h0.z;
        acc.w += e0 * h0.w;
        dsum += e0;
    }

#pragma unroll
    for (int off = 32; off >= NCH4; off >>= 1)
        dsum += __shfl_xor(dsum, off, 64);
#pragma unroll
    for (int off = 32; off >= NCH4; off >>= 1) {
        acc.x += __shfl_down(acc.x, off, 64);
        acc.y += __shfl_down(acc.y, off, 64);
        acc.z += __shfl_down(acc.z, off, 64);
        acc.w += __shfl_down(acc.w, off, 64);
    }

    if (l < NCH4) {
        const float e_self = __expf(sl);
        float4 h = H4[(size_t)node * NCH4 + ch];
        acc.x += e_self * h.x;
        acc.y += e_self * h.y;
        acc.z += e_self * h.z;
        acc.w += e_self * h.w;
        const float inv = 1.f / (dsum + e_self);
        const float4 b4 = reinterpret_cast<const float4*>(bias)[ch];
        float4 r;
        r.x = acc.x * inv + b4.x;
        r.y = acc.y * inv + b4.y;
        r.z = acc.z * inv + b4.z;
        r.w = acc.w * inv + b4.w;
        if (RELU) {
            r.x = fmaxf(r.x, 0.f);
            r.y = fmaxf(r.y, 0.f);
            r.z = fmaxf(r.z, 0.f);
            r.w = fmaxf(r.w, 0.f);
        }
        reinterpret_cast<float4*>(OUT)[(size_t)node * NCH4 + ch] = r;
    }
}

// ---------------- global add pool over sorted batch ----------------
__global__ __launch_bounds__(256) void pool_kernel(const float* __restrict__ H2,
                                                   const int* __restrict__ batch,
                                                   float* __restrict__ out, int N) {
    const int wv = threadIdx.x >> 6;
    const int c = threadIdx.x & 63;
    const int n0 = blockIdx.x * 128 + wv * 32;
    if (n0 >= N) return;
    const int n1 = min(n0 + 32, N);
    float acc = 0.f;
    int cur = batch[n0];
    for (int n = n0; n < n1; ++n) {
        int g = batch[n];
        if (g != cur) {
            atomicAdd(&out[cur * 64 + c], acc);
            acc = 0.f;
            cur = g;
        }
        acc += H2[n * 64 + c];
    }
    atomicAdd(&out[cur * 64 + c], acc);
}

extern "C" void kernel_launch(void* const* d_in, const int* in_sizes, int n_in,
                              void* d_out, int out_size, void* d_ws, size_t ws_size,
                              hipStream_t stream) {
    const float* x = (const float*)d_in[0];
    const int* edge_index = (const int*)d_in[1];
    const int* batch = (const int*)d_in[2];
    const float* W0 = (const float*)d_in[3];
    const float* as0 = (const float*)d_in[4];
    const float* ad0 = (const float*)d_in[5];
    const float* b0 = (const float*)d_in[6];
    const float* W1 = (const float*)d_in[7];
    const float* as1 = (const float*)d_in[8];
    const float* ad1 = (const float*)d_in[9];
    const float* b1 = (const float*)d_in[10];
    const float* W2 = (const float*)d_in[11];
    const float* as2 = (const float*)d_in[12];
    const float* ad2 = (const float*)d_in[13];
    const float* b2 = (const float*)d_in[14];

    const int* e_src = edge_index;            // row 0
    const int* e_dst = edge_index + N_EDGES;  // row 1

    // workspace layout
    float* B0 = (float*)d_ws;                                   // 50000*128 f32
    float* H = B0 + N_NODES * 128;                              // 50000*128 f32
    float* as_ = H + N_NODES * 128;                             // 50000 f32
    float* ad_ = as_ + N_NODES;                                 // 50000 f32
    int* cursor = (int*)(ad_ + N_NODES);                        // 50000 int
    unsigned short* col = (unsigned short*)(cursor + N_NODES);  // 50000*64 ushort
    unsigned int* bin_cursor = (unsigned int*)(col + (size_t)N_NODES * SLOTS);  // NBINS
    unsigned int* bin_buf = bin_cursor + NBINS;                 // NBINS*CAP u32 (~4.8MB)

    hipMemsetAsync(bin_cursor, 0, NBINS * sizeof(unsigned int), stream);

    const int NODE_BLOCKS = (N_NODES + 3) / 4;
    const int GEMM128_BLOCKS = (N_NODES + 31) / 32;

    // ---- layer 0 gemm fused with fill pass-1 (independent -> overlap) ----
    gemm0_fill_kernel<<<P1_BLOCKS + GEMM128_BLOCKS, 256, 0, stream>>>(
        x, W0, as0, ad0, H, as_, ad_, N_NODES, e_src, e_dst, bin_cursor, bin_buf, N_EDGES);
    fill_pass2<<<NBINS, 256, 0, stream>>>(bin_cursor, bin_buf, cursor, col, N_NODES);
    gather_kernel<128, true><<<NODE_BLOCKS, 256, 0, stream>>>(H, as_, ad_, cursor, col, b0, B0, N_NODES);

    // ---- layer 1: B0 -> B0 (relu) ----
    gemm_kernel<128><<<GEMM128_BLOCKS, 256, 0, stream>>>(B0, W1, as1, ad1, H, as_, ad_, N_NODES);
    gather_kernel<128, true><<<NODE_BLOCKS, 256, 0, stream>>>(H, as_, ad_, cursor, col, b1, B0, N_NODES);

    // ---- layer 2: B0 -> B0 (64-wide, no relu) ----
    gemm_kernel<64><<<(N_NODES + 63) / 64, 256, 0, stream>>>(B0, W2, as2, ad2, H, as_, ad_, N_NODES);
    gather_kernel<64, false><<<NODE_BLOCKS, 256, 0, stream>>>(H, as_, ad_, cursor, col, b2, B0, N_NODES);

    // ---- pool ----
    hipMemsetAsync(d_out, 0, (size_t)out_size * sizeof(float), stream);
    pool_kernel<<<(N_NODES + 127) / 128, 256, 0, stream>>>(B0, batch, (float*)d_out, N_NODES);
}

// Round 4
// 311.640 us; speedup vs baseline: 1.2992x; 1.1641x over previous
//
#include <hip/hip_runtime.h>
#include <hip/hip_fp16.h>
#include <math.h>

#define N_NODES 50000
#define N_EDGES 800000
#define N_GRAPHS 64
#define NEG_SLOPE 0.2f
#define SLOTS 64        // bucket capacity; P(in-degree>64) ~ 1e-20 for Poisson(16)

// ---- multisplit fill parameters ----
#define BIN_NODES 256                   // nodes per dst-range bin
#define NBINS 196                       // ceil(50000/256)
#define CAP 6144                        // u32 slots per bin (mean 4082, sigma ~64)
#define P1_BLOCKS 192                   // pass-1 blocks fused ahead of gemm0
#define BATCH 2048                      // edges per block-batch (8 per thread)

__device__ __forceinline__ float leaky(float x) {
    return x > 0.f ? x : NEG_SLOPE * x;
}

// 8-byte chunk of 4 fp16 values
struct __align__(8) half4 {
    __half2 a, b;
};

// ------- GEMM body: H(fp16) = X @ W (f32 compute); as_ = h@a_src, ad_ = h@a_dst -------
// H stored fp16: gather is L2-fill-fabric byte-bound (R3: 410MB/gather at 6.9TB/s);
// halving row bytes is the only lever. All accumulation and alpha math stays f32.
template <int DOUT>
__device__ __forceinline__ void gemm_body(const float* __restrict__ X,
                                          const float* __restrict__ W,
                                          const float* __restrict__ a_src,
                                          const float* __restrict__ a_dst,
                                          half4* __restrict__ H,
                                          float* __restrict__ as_,
                                          float* __restrict__ ad_, int N, int bid,
                                          float* xsmem) {
    constexpr int DIN = 128;
    constexpr int CG = DOUT / 4;   // col groups of 4
    constexpr int RG = 256 / CG;   // row groups of 4
    constexpr int TILE_N = RG * 4;
    float (*xs)[DIN] = reinterpret_cast<float (*)[DIN]>(xsmem);

    const int n0 = bid * TILE_N;
    const int tid = threadIdx.x;

    for (int idx = tid; idx < TILE_N * (DIN / 4); idx += 256) {
        int r = idx / (DIN / 4);
        int q = idx % (DIN / 4);
        int n = n0 + r;
        float4 v = make_float4(0.f, 0.f, 0.f, 0.f);
        if (n < N) v = reinterpret_cast<const float4*>(X)[n * (DIN / 4) + q];
        reinterpret_cast<float4*>(&xs[r][0])[q] = v;
    }
    __syncthreads();

    const int cg = tid % CG;
    const int rg = tid / CG;
    const int c0 = cg * 4;
    const int r0 = rg * 4;

    float acc[4][4] = {};
    for (int k = 0; k < DIN; k += 4) {
        float4 w[4];
#pragma unroll
        for (int kk = 0; kk < 4; ++kk)
            w[kk] = *reinterpret_cast<const float4*>(&W[(k + kk) * DOUT + c0]);
#pragma unroll
        for (int i = 0; i < 4; ++i) {
            float4 xv = *reinterpret_cast<const float4*>(&xs[r0 + i][k]);
            const float xk[4] = {xv.x, xv.y, xv.z, xv.w};
#pragma unroll
            for (int kk = 0; kk < 4; ++kk) {
                acc[i][0] += xk[kk] * w[kk].x;
                acc[i][1] += xk[kk] * w[kk].y;
                acc[i][2] += xk[kk] * w[kk].z;
                acc[i][3] += xk[kk] * w[kk].w;
            }
        }
    }

    const float4 asv = *reinterpret_cast<const float4*>(&a_src[c0]);
    const float4 adv = *reinterpret_cast<const float4*>(&a_dst[c0]);
#pragma unroll
    for (int i = 0; i < 4; ++i) {
        const int n = n0 + r0 + i;
        if (n < N) {
            half4 o;
            o.a = __floats2half2_rn(acc[i][0], acc[i][1]);
            o.b = __floats2half2_rn(acc[i][2], acc[i][3]);
            H[(size_t)n * CG + cg] = o;
        }
        float ps = acc[i][0] * asv.x + acc[i][1] * asv.y + acc[i][2] * asv.z + acc[i][3] * asv.w;
        float pd = acc[i][0] * adv.x + acc[i][1] * adv.y + acc[i][2] * adv.z + acc[i][3] * adv.w;
#pragma unroll
        for (int off = CG / 2; off; off >>= 1) {
            ps += __shfl_xor(ps, off, 64);
            pd += __shfl_xor(pd, off, 64);
        }
        if (cg == 0 && n < N) {
            as_[n] = ps;
            ad_[n] = pd;
        }
    }
}

template <int DOUT>
__global__ __launch_bounds__(256) void gemm_kernel(const float* __restrict__ X,
                                                   const float* __restrict__ W,
                                                   const float* __restrict__ a_src,
                                                   const float* __restrict__ a_dst,
                                                   half4* __restrict__ H,
                                                   float* __restrict__ as_,
                                                   float* __restrict__ ad_, int N) {
    constexpr int TILE_N = (256 / (DOUT / 4)) * 4;
    __shared__ __align__(16) float xs[TILE_N][128];
    gemm_body<DOUT>(X, W, a_src, a_dst, H, as_, ad_, N, blockIdx.x, &xs[0][0]);
}

// ------- pass 1: multisplit edges into 196 dst-range bins (packed u32 = d<<16|s) -------
struct P1Smem {
    unsigned int stage[BATCH];
    int hist[NBINS];
    int off[NBINS];
    unsigned int gbase[NBINS];
    int total;
};

__device__ __forceinline__ void fill_pass1(const int* __restrict__ src,
                                           const int* __restrict__ dst,
                                           unsigned int* __restrict__ bin_cursor,
                                           unsigned int* __restrict__ bin_buf,
                                           int E, int bid, void* smem_raw) {
    P1Smem& S = *reinterpret_cast<P1Smem*>(smem_raw);
    const int tid = threadIdx.x;
    const int nbatch = (E + BATCH - 1) / BATCH;
    for (int b = bid; b < nbatch; b += P1_BLOCKS) {
        __syncthreads();  // protect stage/hist reuse across batches
        for (int i = tid; i < NBINS; i += 256) S.hist[i] = 0;
        const int e0 = b * BATCH;
        unsigned int pk[8];
        int rk[8];
        bool ok[8];
#pragma unroll
        for (int k = 0; k < 8; ++k) {
            int e = e0 + tid + k * 256;
            ok[k] = (e < E);
            int d = ok[k] ? dst[e] : 0;
            int s = ok[k] ? src[e] : 0;
            pk[k] = ((unsigned)d << 16) | (unsigned)s;
            rk[k] = 0;
        }
        __syncthreads();
#pragma unroll
        for (int k = 0; k < 8; ++k)
            if (ok[k]) rk[k] = atomicAdd(&S.hist[pk[k] >> 24], 1);
        __syncthreads();
        if (tid == 0) {
            int run = 0;
            for (int i = 0; i < NBINS; ++i) {
                S.off[i] = run;
                run += S.hist[i];
            }
            S.total = run;
        }
        __syncthreads();
        if (tid < NBINS && S.hist[tid] > 0)
            S.gbase[tid] = atomicAdd(&bin_cursor[tid], (unsigned)S.hist[tid]);
#pragma unroll
        for (int k = 0; k < 8; ++k)
            if (ok[k]) S.stage[S.off[pk[k] >> 24] + rk[k]] = pk[k];
        __syncthreads();
        const int tot = S.total;
        for (int i = tid; i < tot; i += 256) {
            unsigned int v = S.stage[i];
            int bn = v >> 24;
            unsigned int p = S.gbase[bn] + (unsigned)(i - S.off[bn]);
            if (p < CAP) bin_buf[(size_t)bn * CAP + p] = v;
        }
    }
}

// ------- fused layer-0 GEMM + pass-1 (independent dataflow -> overlap) -------
__global__ __launch_bounds__(256) void gemm0_fill_kernel(
    const float* __restrict__ X, const float* __restrict__ W,
    const float* __restrict__ a_src, const float* __restrict__ a_dst,
    half4* __restrict__ H, float* __restrict__ as_, float* __restrict__ ad_, int N,
    const int* __restrict__ src, const int* __restrict__ dst,
    unsigned int* __restrict__ bin_cursor, unsigned int* __restrict__ bin_buf, int E) {
    __shared__ __align__(16) unsigned char smem[16384];  // union: P1Smem (10.5KB) / xs (16KB)
    if (blockIdx.x < P1_BLOCKS) {
        fill_pass1(src, dst, bin_cursor, bin_buf, E, blockIdx.x, smem);
        return;
    }
    gemm_body<128>(X, W, a_src, a_dst, H, as_, ad_, N, blockIdx.x - P1_BLOCKS,
                   reinterpret_cast<float*>(smem));
}

// ------- pass 2: per-bin bucket build in LDS, coalesced writeback -------
__global__ __launch_bounds__(256) void fill_pass2(const unsigned int* __restrict__ bin_cursor,
                                                  const unsigned int* __restrict__ bin_buf,
                                                  int* __restrict__ cursor,
                                                  unsigned short* __restrict__ col, int N) {
    __shared__ unsigned short bk[BIN_NODES][SLOTS];  // 32KB
    __shared__ int cnt[BIN_NODES];                   // 1KB
    const int b = blockIdx.x;
    const int tid = threadIdx.x;
    const int base = b * BIN_NODES;
    const int nn = min(BIN_NODES, N - base);
    if (nn <= 0) return;
    cnt[tid] = 0;
    __syncthreads();
    const int ec = min((int)bin_cursor[b], CAP);
    for (int i = tid; i < ec; i += 256) {
        unsigned int v = bin_buf[(size_t)b * CAP + i];
        int d = (int)(v >> 16) - base;  // in [0, BIN_NODES)
        int p = atomicAdd(&cnt[d], 1);
        if (p < SLOTS) bk[d][p] = (unsigned short)(v & 0xFFFFu);
    }
    __syncthreads();
    unsigned int* col32 = reinterpret_cast<unsigned int*>(col);
    const unsigned int* lds32 = reinterpret_cast<const unsigned int*>(&bk[0][0]);
    const int words = nn * (SLOTS / 2);
    for (int i = tid; i < words; i += 256)
        col32[(size_t)base * (SLOTS / 2) + i] = lds32[i];
    if (tid < nn) cursor[base + tid] = cnt[tid];
}

// ------- fused softmax + gather per dst node (wave per node, no max pass) -------
// H is fp16 (half4 chunks); all accumulation f32.
template <int DOUT, bool RELU>
__global__ __launch_bounds__(256) void gather_kernel(const half4* __restrict__ H,
                                                     const float* __restrict__ as_,
                                                     const float* __restrict__ ad_,
                                                     const int* __restrict__ cursor,
                                                     const unsigned short* __restrict__ col,
                                                     const float* __restrict__ bias,
                                                     float* __restrict__ OUT, int N) {
    constexpr int NCH4 = DOUT / 4;               // lanes per edge: 32 or 16
    constexpr int SUBS = 64 / NCH4;              // subgroups: 2 or 4
    const int node = blockIdx.x * 4 + (threadIdx.x >> 6);
    if (node >= N) return;
    const int l = threadIdx.x & 63;
    const int ch = l & (NCH4 - 1);
    const int sub = l / NCH4;

    const float adn = ad_[node];
    const float sl = leaky(as_[node] + adn);
    const int rs = node << 6;
    const int re = rs + min(cursor[node], SLOTS);

    float4 acc = make_float4(0.f, 0.f, 0.f, 0.f);
    float dsum = 0.f;

    int i = rs + sub;
    for (; i + 7 * SUBS < re; i += 8 * SUBS) {
        int s[8];
        float a[8];
        half4 h[8];
#pragma unroll
        for (int u = 0; u < 8; ++u) s[u] = col[i + u * SUBS];
#pragma unroll
        for (int u = 0; u < 8; ++u) a[u] = as_[s[u]];
#pragma unroll
        for (int u = 0; u < 8; ++u) h[u] = H[(size_t)s[u] * NCH4 + ch];
#pragma unroll
        for (int u = 0; u < 8; ++u) {
            float ee = __expf(leaky(a[u] + adn));
            float2 f0 = __half22float2(h[u].a);
            float2 f1 = __half22float2(h[u].b);
            acc.x += ee * f0.x;
            acc.y += ee * f0.y;
            acc.z += ee * f1.x;
            acc.w += ee * f1.y;
            dsum += ee;
        }
    }
    for (; i + 3 * SUBS < re; i += 4 * SUBS) {
        int s[4];
        float a[4];
        half4 h[4];
#pragma unroll
        for (int u = 0; u < 4; ++u) s[u] = col[i + u * SUBS];
#pragma unroll
        for (int u = 0; u < 4; ++u) a[u] = as_[s[u]];
#pragma unroll
        for (int u = 0; u < 4; ++u) h[u] = H[(size_t)s[u] * NCH4 + ch];
#pragma unroll
        for (int u = 0; u < 4; ++u) {
            float ee = __expf(leaky(a[u] + adn));
            float2 f0 = __half22float2(h[u].a);
            float2 f1 = __half22float2(h[u].b);
            acc.x += ee * f0.x;
            acc.y += ee * f0.y;
            acc.z += ee * f1.x;
            acc.w += ee * f1.y;
            dsum += ee;
        }
    }
    for (; i < re; i += SUBS) {
        int s0 = col[i];
        float e0 = __expf(leaky(as_[s0] + adn));
        half4 h0 = H[(size_t)s0 * NCH4 + ch];
        float2 f0 = __half22float2(h0.a);
        float2 f1 = __half22float2(h0.b);
        acc.x += e0 * f0.x;
        acc.y += e0 * f0.y;
        acc.z += e0 * f1.x;
        acc.w += e0 * f1.y;
        dsum += e0;
    }

#pragma unroll
    for (int off = 32; off >= NCH4; off >>= 1)
        dsum += __shfl_xor(dsum, off, 64);
#pragma unroll
    for (int off = 32; off >= NCH4; off >>= 1) {
        acc.x += __shfl_down(acc.x, off, 64);
        acc.y += __shfl_down(acc.y, off, 64);
        acc.z += __shfl_down(acc.z, off, 64);
        acc.w += __shfl_down(acc.w, off, 64);
    }

    if (l < NCH4) {
        const float e_self = __expf(sl);
        half4 h = H[(size_t)node * NCH4 + ch];
        float2 f0 = __half22float2(h.a);
        float2 f1 = __half22float2(h.b);
        acc.x += e_self * f0.x;
        acc.y += e_self * f0.y;
        acc.z += e_self * f1.x;
        acc.w += e_self * f1.y;
        const float inv = 1.f / (dsum + e_self);
        const float4 b4 = reinterpret_cast<const float4*>(bias)[ch];
        float4 r;
        r.x = acc.x * inv + b4.x;
        r.y = acc.y * inv + b4.y;
        r.z = acc.z * inv + b4.z;
        r.w = acc.w * inv + b4.w;
        if (RELU) {
            r.x = fmaxf(r.x, 0.f);
            r.y = fmaxf(r.y, 0.f);
            r.z = fmaxf(r.z, 0.f);
            r.w = fmaxf(r.w, 0.f);
        }
        reinterpret_cast<float4*>(OUT)[(size_t)node * NCH4 + ch] = r;
    }
}

// ---------------- global add pool over sorted batch ----------------
__global__ __launch_bounds__(256) void pool_kernel(const float* __restrict__ H2,
                                                   const int* __restrict__ batch,
                                                   float* __restrict__ out, int N) {
    const int wv = threadIdx.x >> 6;
    const int c = threadIdx.x & 63;
    const int n0 = blockIdx.x * 128 + wv * 32;
    if (n0 >= N) return;
    const int n1 = min(n0 + 32, N);
    float acc = 0.f;
    int cur = batch[n0];
    for (int n = n0; n < n1; ++n) {
        int g = batch[n];
        if (g != cur) {
            atomicAdd(&out[cur * 64 + c], acc);
            acc = 0.f;
            cur = g;
        }
        acc += H2[n * 64 + c];
    }
    atomicAdd(&out[cur * 64 + c], acc);
}

extern "C" void kernel_launch(void* const* d_in, const int* in_sizes, int n_in,
                              void* d_out, int out_size, void* d_ws, size_t ws_size,
                              hipStream_t stream) {
    const float* x = (const float*)d_in[0];
    const int* edge_index = (const int*)d_in[1];
    const int* batch = (const int*)d_in[2];
    const float* W0 = (const float*)d_in[3];
    const float* as0 = (const float*)d_in[4];
    const float* ad0 = (const float*)d_in[5];
    const float* b0 = (const float*)d_in[6];
    const float* W1 = (const float*)d_in[7];
    const float* as1 = (const float*)d_in[8];
    const float* ad1 = (const float*)d_in[9];
    const float* b1 = (const float*)d_in[10];
    const float* W2 = (const float*)d_in[11];
    const float* as2 = (const float*)d_in[12];
    const float* ad2 = (const float*)d_in[13];
    const float* b2 = (const float*)d_in[14];

    const int* e_src = edge_index;            // row 0
    const int* e_dst = edge_index + N_EDGES;  // row 1

    // workspace layout (H region kept at f32 footprint; only half used by fp16 H)
    float* B0 = (float*)d_ws;                                   // 50000*128 f32
    half4* H = (half4*)(B0 + N_NODES * 128);                    // 50000*128 fp16 (12.8MB)
    float* as_ = (float*)H + N_NODES * 128;                     // 50000 f32 (offset in f32 units)
    float* ad_ = as_ + N_NODES;                                 // 50000 f32
    int* cursor = (int*)(ad_ + N_NODES);                        // 50000 int
    unsigned short* col = (unsigned short*)(cursor + N_NODES);  // 50000*64 ushort
    unsigned int* bin_cursor = (unsigned int*)(col + (size_t)N_NODES * SLOTS);  // NBINS
    unsigned int* bin_buf = bin_cursor + NBINS;                 // NBINS*CAP u32 (~4.8MB)

    hipMemsetAsync(bin_cursor, 0, NBINS * sizeof(unsigned int), stream);

    const int NODE_BLOCKS = (N_NODES + 3) / 4;
    const int GEMM128_BLOCKS = (N_NODES + 31) / 32;

    // ---- layer 0 gemm fused with fill pass-1 (independent -> overlap) ----
    gemm0_fill_kernel<<<P1_BLOCKS + GEMM128_BLOCKS, 256, 0, stream>>>(
        x, W0, as0, ad0, H, as_, ad_, N_NODES, e_src, e_dst, bin_cursor, bin_buf, N_EDGES);
    fill_pass2<<<NBINS, 256, 0, stream>>>(bin_cursor, bin_buf, cursor, col, N_NODES);
    gather_kernel<128, true><<<NODE_BLOCKS, 256, 0, stream>>>(H, as_, ad_, cursor, col, b0, B0, N_NODES);

    // ---- layer 1: B0 -> B0 (relu) ----
    gemm_kernel<128><<<GEMM128_BLOCKS, 256, 0, stream>>>(B0, W1, as1, ad1, H, as_, ad_, N_NODES);
    gather_kernel<128, true><<<NODE_BLOCKS, 256, 0, stream>>>(H, as_, ad_, cursor, col, b1, B0, N_NODES);

    // ---- layer 2: B0 -> B0 (64-wide, no relu) ----
    gemm_kernel<64><<<(N_NODES + 63) / 64, 256, 0, stream>>>(B0, W2, as2, ad2, H, as_, ad_, N_NODES);
    gather_kernel<64, false><<<NODE_BLOCKS, 256, 0, stream>>>(H, as_, ad_, cursor, col, b2, B0, N_NODES);

    // ---- pool ----
    hipMemsetAsync(d_out, 0, (size_t)out_size * sizeof(float), stream);
    pool_kernel<<<(N_NODES + 127) / 128, 256, 0, stream>>>(B0, batch, (float*)d_out, N_NODES);
}

// Round 5
// 267.605 us; speedup vs baseline: 1.5130x; 1.1646x over previous
//
#include <hip/hip_runtime.h>
#include <hip/hip_fp16.h>
#include <math.h>

#define N_NODES 50000
#define N_EDGES 800000
#define N_GRAPHS 64
#define NEG_SLOPE 0.2f
#define SLOTS 64        // bucket capacity; P(in-degree>64) ~ 1e-20 for Poisson(16)

// ---- multisplit fill parameters ----
#define BIN_NODES 256                   // nodes per dst-range bin
#define NBINS 196                       // ceil(50000/256)
#define CAP 6144                        // u32 slots per bin (mean 4082, sigma ~64)
#define P1_BLOCKS 192                   // pass-1 blocks fused ahead of gemm0
#define BATCH 2048                      // edges per block-batch (8 per thread)

typedef _Float16 f16x8 __attribute__((ext_vector_type(8)));
typedef float f32x4 __attribute__((ext_vector_type(4)));

__device__ __forceinline__ float leaky(float x) {
    return x > 0.f ? x : NEG_SLOPE * x;
}

// 8-byte chunk of 4 fp16 values (gather load granule)
struct __align__(8) half4 {
    __half2 a, b;
};

// ------- prep: W -> MFMA lane-major fp16 fragments; also zeroes bin_cursor -------
// Wt layout: [kt][ct][lane][8] halves; lane l supplies B[k=kt*32+(l>>4)*8+b][c=ct*16+(l&15)].
__global__ __launch_bounds__(256) void prep_kernel(const float* __restrict__ W0,
                                                   const float* __restrict__ W1,
                                                   const float* __restrict__ W2,
                                                   _Float16* __restrict__ Wt0,
                                                   _Float16* __restrict__ Wt1,
                                                   _Float16* __restrict__ Wt2,
                                                   unsigned int* __restrict__ bin_cursor) {
    const int t = blockIdx.x * 256 + threadIdx.x;
    if (t < NBINS) bin_cursor[t] = 0;
    const float* W;
    _Float16* Wt;
    int g, CTl, DOUTl;
    if (t < 2048) { W = W0; Wt = Wt0; g = t; CTl = 8; DOUTl = 128; }
    else if (t < 4096) { W = W1; Wt = Wt1; g = t - 2048; CTl = 8; DOUTl = 128; }
    else if (t < 5120) { W = W2; Wt = Wt2; g = t - 4096; CTl = 4; DOUTl = 64; }
    else return;
    const int kt = g / (CTl * 64);
    const int rem = g % (CTl * 64);
    const int ct = rem / 64;
    const int lane = rem % 64;
    const int kbase = kt * 32 + (lane >> 4) * 8;
    const int c = ct * 16 + (lane & 15);
#pragma unroll
    for (int b = 0; b < 8; ++b)
        Wt[(size_t)g * 8 + b] = (_Float16)W[(size_t)(kbase + b) * DOUTl + c];
}

// ------- MFMA GEMM body: H(fp16) = X @ W; as_ = h@a_src, ad_ = h@a_dst -------
// Block = 64 rows x DOUT cols, 4 waves x 16 rows. K=128 via 4x mfma_f32_16x16x32_f16.
// xs: 64x128 fp16 in LDS, 16B-chunk XOR swizzle (q ^ (row&15)) -> conflict-free A reads.
template <int DOUT>
__device__ __forceinline__ void mfma_gemm_body(const float* __restrict__ X,
                                               const _Float16* __restrict__ Wt,
                                               const float* __restrict__ a_src,
                                               const float* __restrict__ a_dst,
                                               _Float16* __restrict__ H,
                                               float* __restrict__ as_,
                                               float* __restrict__ ad_, int N, int bid,
                                               _Float16* xs) {
    constexpr int CT = DOUT / 16;
    const int tid = threadIdx.x;
    const int n0 = bid * 64;
    const float4* X4 = reinterpret_cast<const float4*>(X);

    for (int idx = tid; idx < 64 * 16; idx += 256) {
        const int r = idx >> 4, q = idx & 15;
        const int n = n0 + r;
        float4 v0 = make_float4(0.f, 0.f, 0.f, 0.f), v1 = v0;
        if (n < N) {
            v0 = X4[(size_t)n * 32 + 2 * q];
            v1 = X4[(size_t)n * 32 + 2 * q + 1];
        }
        f16x8 hv;
        hv[0] = (_Float16)v0.x; hv[1] = (_Float16)v0.y;
        hv[2] = (_Float16)v0.z; hv[3] = (_Float16)v0.w;
        hv[4] = (_Float16)v1.x; hv[5] = (_Float16)v1.y;
        hv[6] = (_Float16)v1.z; hv[7] = (_Float16)v1.w;
        *reinterpret_cast<f16x8*>(&xs[r * 128 + ((q ^ (r & 15)) << 3)]) = hv;
    }
    __syncthreads();

    const int wave = tid >> 6, lane = tid & 63;
    const int colb = lane & 15;   // col within 16-tile; also A-row within wave tile
    const int kg = lane >> 4;     // k-group 0..3 (A); row-group (C/D)
    const int arow = wave * 16 + colb;

    f32x4 acc[CT];
#pragma unroll
    for (int ct = 0; ct < CT; ++ct) {
        acc[ct][0] = 0.f; acc[ct][1] = 0.f; acc[ct][2] = 0.f; acc[ct][3] = 0.f;
    }
    const f16x8* Wt8 = reinterpret_cast<const f16x8*>(Wt);
#pragma unroll
    for (int kt = 0; kt < 4; ++kt) {
        f16x8 A = *reinterpret_cast<const f16x8*>(
            &xs[arow * 128 + (((kt * 4 + kg) ^ (arow & 15)) << 3)]);
#pragma unroll
        for (int ct = 0; ct < CT; ++ct) {
            f16x8 B = Wt8[(kt * CT + ct) * 64 + lane];
            acc[ct] = __builtin_amdgcn_mfma_f32_16x16x32_f16(A, B, acc[ct], 0, 0, 0);
        }
    }

    // epilogue: H store (fp16) + alpha partials from f32 accs
    float ps[4] = {0.f, 0.f, 0.f, 0.f}, pd[4] = {0.f, 0.f, 0.f, 0.f};
#pragma unroll
    for (int ct = 0; ct < CT; ++ct) {
        const int col = ct * 16 + colb;
        const float asv = a_src[col];
        const float adv = a_dst[col];
#pragma unroll
        for (int r = 0; r < 4; ++r) {
            const float d = acc[ct][r];
            ps[r] += d * asv;
            pd[r] += d * adv;
            const int row = n0 + wave * 16 + kg * 4 + r;
            if (row < N) H[(size_t)row * DOUT + col] = (_Float16)d;
        }
    }
#pragma unroll
    for (int off = 1; off < 16; off <<= 1) {
#pragma unroll
        for (int r = 0; r < 4; ++r) {
            ps[r] += __shfl_xor(ps[r], off, 64);
            pd[r] += __shfl_xor(pd[r], off, 64);
        }
    }
    if (colb == 0) {
#pragma unroll
        for (int r = 0; r < 4; ++r) {
            const int row = n0 + wave * 16 + kg * 4 + r;
            if (row < N) {
                as_[row] = ps[r];
                ad_[row] = pd[r];
            }
        }
    }
}

template <int DOUT>
__global__ __launch_bounds__(256) void mfma_gemm_kernel(const float* __restrict__ X,
                                                        const _Float16* __restrict__ Wt,
                                                        const float* __restrict__ a_src,
                                                        const float* __restrict__ a_dst,
                                                        _Float16* __restrict__ H,
                                                        float* __restrict__ as_,
                                                        float* __restrict__ ad_, int N) {
    __shared__ __align__(16) _Float16 xs[64 * 128];
    mfma_gemm_body<DOUT>(X, Wt, a_src, a_dst, H, as_, ad_, N, blockIdx.x, xs);
}

// ------- pass 1: multisplit edges into 196 dst-range bins (packed u32 = d<<16|s) -------
struct P1Smem {
    unsigned int stage[BATCH];
    int hist[NBINS];
    int off[NBINS];
    unsigned int gbase[NBINS];
    int total;
};

__device__ __forceinline__ void fill_pass1(const int* __restrict__ src,
                                           const int* __restrict__ dst,
                                           unsigned int* __restrict__ bin_cursor,
                                           unsigned int* __restrict__ bin_buf,
                                           int E, int bid, void* smem_raw) {
    P1Smem& S = *reinterpret_cast<P1Smem*>(smem_raw);
    const int tid = threadIdx.x;
    const int nbatch = (E + BATCH - 1) / BATCH;
    for (int b = bid; b < nbatch; b += P1_BLOCKS) {
        __syncthreads();  // protect stage/hist reuse across batches
        for (int i = tid; i < NBINS; i += 256) S.hist[i] = 0;
        const int e0 = b * BATCH;
        unsigned int pk[8];
        int rk[8];
        bool ok[8];
#pragma unroll
        for (int k = 0; k < 8; ++k) {
            int e = e0 + tid + k * 256;
            ok[k] = (e < E);
            int d = ok[k] ? dst[e] : 0;
            int s = ok[k] ? src[e] : 0;
            pk[k] = ((unsigned)d << 16) | (unsigned)s;
            rk[k] = 0;
        }
        __syncthreads();
#pragma unroll
        for (int k = 0; k < 8; ++k)
            if (ok[k]) rk[k] = atomicAdd(&S.hist[pk[k] >> 24], 1);
        __syncthreads();
        if (tid == 0) {
            int run = 0;
            for (int i = 0; i < NBINS; ++i) {
                S.off[i] = run;
                run += S.hist[i];
            }
            S.total = run;
        }
        __syncthreads();
        if (tid < NBINS && S.hist[tid] > 0)
            S.gbase[tid] = atomicAdd(&bin_cursor[tid], (unsigned)S.hist[tid]);
#pragma unroll
        for (int k = 0; k < 8; ++k)
            if (ok[k]) S.stage[S.off[pk[k] >> 24] + rk[k]] = pk[k];
        __syncthreads();
        const int tot = S.total;
        for (int i = tid; i < tot; i += 256) {
            unsigned int v = S.stage[i];
            int bn = v >> 24;
            unsigned int p = S.gbase[bn] + (unsigned)(i - S.off[bn]);
            if (p < CAP) bin_buf[(size_t)bn * CAP + p] = v;
        }
    }
}

// ------- fused layer-0 MFMA GEMM + pass-1 (independent dataflow -> overlap) -------
__global__ __launch_bounds__(256) void gemm0_fill_kernel(
    const float* __restrict__ X, const _Float16* __restrict__ Wt0,
    const float* __restrict__ a_src, const float* __restrict__ a_dst,
    _Float16* __restrict__ H, float* __restrict__ as_, float* __restrict__ ad_, int N,
    const int* __restrict__ src, const int* __restrict__ dst,
    unsigned int* __restrict__ bin_cursor, unsigned int* __restrict__ bin_buf, int E) {
    __shared__ __align__(16) unsigned char smem[16384];  // union: P1Smem (10.5KB) / xs (16KB)
    if (blockIdx.x < P1_BLOCKS) {
        fill_pass1(src, dst, bin_cursor, bin_buf, E, blockIdx.x, smem);
        return;
    }
    mfma_gemm_body<128>(X, Wt0, a_src, a_dst, H, as_, ad_, N, blockIdx.x - P1_BLOCKS,
                        reinterpret_cast<_Float16*>(smem));
}

// ------- pass 2: per-bin bucket build in LDS, coalesced writeback -------
__global__ __launch_bounds__(256) void fill_pass2(const unsigned int* __restrict__ bin_cursor,
                                                  const unsigned int* __restrict__ bin_buf,
                                                  int* __restrict__ cursor,
                                                  unsigned short* __restrict__ col, int N) {
    __shared__ unsigned short bk[BIN_NODES][SLOTS];  // 32KB
    __shared__ int cnt[BIN_NODES];                   // 1KB
    const int b = blockIdx.x;
    const int tid = threadIdx.x;
    const int base = b * BIN_NODES;
    const int nn = min(BIN_NODES, N - base);
    if (nn <= 0) return;
    cnt[tid] = 0;
    __syncthreads();
    const int ec = min((int)bin_cursor[b], CAP);
    for (int i = tid; i < ec; i += 256) {
        unsigned int v = bin_buf[(size_t)b * CAP + i];
        int d = (int)(v >> 16) - base;  // in [0, BIN_NODES)
        int p = atomicAdd(&cnt[d], 1);
        if (p < SLOTS) bk[d][p] = (unsigned short)(v & 0xFFFFu);
    }
    __syncthreads();
    unsigned int* col32 = reinterpret_cast<unsigned int*>(col);
    const unsigned int* lds32 = reinterpret_cast<const unsigned int*>(&bk[0][0]);
    const int words = nn * (SLOTS / 2);
    for (int i = tid; i < words; i += 256)
        col32[(size_t)base * (SLOTS / 2) + i] = lds32[i];
    if (tid < nn) cursor[base + tid] = cnt[tid];
}

// ------- fused softmax + gather per dst node (wave per node, no max pass) -------
// H is fp16 (half4 chunks); all accumulation f32.
template <int DOUT, bool RELU>
__global__ __launch_bounds__(256) void gather_kernel(const half4* __restrict__ H,
                                                     const float* __restrict__ as_,
                                                     const float* __restrict__ ad_,
                                                     const int* __restrict__ cursor,
                                                     const unsigned short* __restrict__ col,
                                                     const float* __restrict__ bias,
                                                     float* __restrict__ OUT, int N) {
    constexpr int NCH4 = DOUT / 4;               // lanes per edge: 32 or 16
    constexpr int SUBS = 64 / NCH4;              // subgroups: 2 or 4
    const int node = blockIdx.x * 4 + (threadIdx.x >> 6);
    if (node >= N) return;
    const int l = threadIdx.x & 63;
    const int ch = l & (NCH4 - 1);
    const int sub = l / NCH4;

    const float adn = ad_[node];
    const float sl = leaky(as_[node] + adn);
    const int rs = node << 6;
    const int re = rs + min(cursor[node], SLOTS);

    float4 acc = make_float4(0.f, 0.f, 0.f, 0.f);
    float dsum = 0.f;

    int i = rs + sub;
    for (; i + 7 * SUBS < re; i += 8 * SUBS) {
        int s[8];
        float a[8];
        half4 h[8];
#pragma unroll
        for (int u = 0; u < 8; ++u) s[u] = col[i + u * SUBS];
#pragma unroll
        for (int u = 0; u < 8; ++u) a[u] = as_[s[u]];
#pragma unroll
        for (int u = 0; u < 8; ++u) h[u] = H[(size_t)s[u] * NCH4 + ch];
#pragma unroll
        for (int u = 0; u < 8; ++u) {
            float ee = __expf(leaky(a[u] + adn));
            float2 f0 = __half22float2(h[u].a);
            float2 f1 = __half22float2(h[u].b);
            acc.x += ee * f0.x;
            acc.y += ee * f0.y;
            acc.z += ee * f1.x;
            acc.w += ee * f1.y;
            dsum += ee;
        }
    }
    for (; i + 3 * SUBS < re; i += 4 * SUBS) {
        int s[4];
        float a[4];
        half4 h[4];
#pragma unroll
        for (int u = 0; u < 4; ++u) s[u] = col[i + u * SUBS];
#pragma unroll
        for (int u = 0; u < 4; ++u) a[u] = as_[s[u]];
#pragma unroll
        for (int u = 0; u < 4; ++u) h[u] = H[(size_t)s[u] * NCH4 + ch];
#pragma unroll
        for (int u = 0; u < 4; ++u) {
            float ee = __expf(leaky(a[u] + adn));
            float2 f0 = __half22float2(h[u].a);
            float2 f1 = __half22float2(h[u].b);
            acc.x += ee * f0.x;
            acc.y += ee * f0.y;
            acc.z += ee * f1.x;
            acc.w += ee * f1.y;
            dsum += ee;
        }
    }
    for (; i < re; i += SUBS) {
        int s0 = col[i];
        float e0 = __expf(leaky(as_[s0] + adn));
        half4 h0 = H[(size_t)s0 * NCH4 + ch];
        float2 f0 = __half22float2(h0.a);
        float2 f1 = __half22float2(h0.b);
        acc.x += e0 * f0.x;
        acc.y += e0 * f0.y;
        acc.z += e0 * f1.x;
        acc.w += e0 * f1.y;
        dsum += e0;
    }

#pragma unroll
    for (int off = 32; off >= NCH4; off >>= 1)
        dsum += __shfl_xor(dsum, off, 64);
#pragma unroll
    for (int off = 32; off >= NCH4; off >>= 1) {
        acc.x += __shfl_down(acc.x, off, 64);
        acc.y += __shfl_down(acc.y, off, 64);
        acc.z += __shfl_down(acc.z, off, 64);
        acc.w += __shfl_down(acc.w, off, 64);
    }

    if (l < NCH4) {
        const float e_self = __expf(sl);
        half4 h = H[(size_t)node * NCH4 + ch];
        float2 f0 = __half22float2(h.a);
        float2 f1 = __half22float2(h.b);
        acc.x += e_self * f0.x;
        acc.y += e_self * f0.y;
        acc.z += e_self * f1.x;
        acc.w += e_self * f1.y;
        const float inv = 1.f / (dsum + e_self);
        const float4 b4 = reinterpret_cast<const float4*>(bias)[ch];
        float4 r;
        r.x = acc.x * inv + b4.x;
        r.y = acc.y * inv + b4.y;
        r.z = acc.z * inv + b4.z;
        r.w = acc.w * inv + b4.w;
        if (RELU) {
            r.x = fmaxf(r.x, 0.f);
            r.y = fmaxf(r.y, 0.f);
            r.z = fmaxf(r.z, 0.f);
            r.w = fmaxf(r.w, 0.f);
        }
        reinterpret_cast<float4*>(OUT)[(size_t)node * NCH4 + ch] = r;
    }
}

// ---------------- global add pool over sorted batch ----------------
__global__ __launch_bounds__(256) void pool_kernel(const float* __restrict__ H2,
                                                   const int* __restrict__ batch,
                                                   float* __restrict__ out, int N) {
    const int wv = threadIdx.x >> 6;
    const int c = threadIdx.x & 63;
    const int n0 = blockIdx.x * 128 + wv * 32;
    if (n0 >= N) return;
    const int n1 = min(n0 + 32, N);
    float acc = 0.f;
    int cur = batch[n0];
    for (int n = n0; n < n1; ++n) {
        int g = batch[n];
        if (g != cur) {
            atomicAdd(&out[cur * 64 + c], acc);
            acc = 0.f;
            cur = g;
        }
        acc += H2[n * 64 + c];
    }
    atomicAdd(&out[cur * 64 + c], acc);
}

extern "C" void kernel_launch(void* const* d_in, const int* in_sizes, int n_in,
                              void* d_out, int out_size, void* d_ws, size_t ws_size,
                              hipStream_t stream) {
    const float* x = (const float*)d_in[0];
    const int* edge_index = (const int*)d_in[1];
    const int* batch = (const int*)d_in[2];
    const float* W0 = (const float*)d_in[3];
    const float* as0 = (const float*)d_in[4];
    const float* ad0 = (const float*)d_in[5];
    const float* b0 = (const float*)d_in[6];
    const float* W1 = (const float*)d_in[7];
    const float* as1 = (const float*)d_in[8];
    const float* ad1 = (const float*)d_in[9];
    const float* b1 = (const float*)d_in[10];
    const float* W2 = (const float*)d_in[11];
    const float* as2 = (const float*)d_in[12];
    const float* ad2 = (const float*)d_in[13];
    const float* b2 = (const float*)d_in[14];

    const int* e_src = edge_index;            // row 0
    const int* e_dst = edge_index + N_EDGES;  // row 1

    // workspace layout (byte-based; every region 16B-aligned)
    char* p = (char*)d_ws;
    float* B0 = (float*)p;            p += (size_t)N_NODES * 128 * 4;   // 25.6MB
    _Float16* H = (_Float16*)p;       p += (size_t)N_NODES * 128 * 2;   // 12.8MB
    float* as_ = (float*)p;           p += (size_t)N_NODES * 4;
    float* ad_ = (float*)p;           p += (size_t)N_NODES * 4;
    int* cursor = (int*)p;            p += (size_t)N_NODES * 4;
    unsigned short* col = (unsigned short*)p; p += (size_t)N_NODES * SLOTS * 2;  // 6.4MB
    unsigned int* bin_cursor = (unsigned int*)p; p += (size_t)NBINS * 4;
    unsigned int* bin_buf = (unsigned int*)p; p += (size_t)NBINS * CAP * 4;      // 4.8MB
    _Float16* Wt0 = (_Float16*)p;     p += (size_t)16384 * 2;
    _Float16* Wt1 = (_Float16*)p;     p += (size_t)16384 * 2;
    _Float16* Wt2 = (_Float16*)p;     p += (size_t)8192 * 2;

    const int NODE_BLOCKS = (N_NODES + 3) / 4;
    const int GEMM_BLOCKS = (N_NODES + 63) / 64;

    // ---- prep: W fragments + bin_cursor zero ----
    prep_kernel<<<20, 256, 0, stream>>>(W0, W1, W2, Wt0, Wt1, Wt2, bin_cursor);

    // ---- layer 0 MFMA gemm fused with fill pass-1 (independent -> overlap) ----
    gemm0_fill_kernel<<<P1_BLOCKS + GEMM_BLOCKS, 256, 0, stream>>>(
        x, Wt0, as0, ad0, H, as_, ad_, N_NODES, e_src, e_dst, bin_cursor, bin_buf, N_EDGES);
    fill_pass2<<<NBINS, 256, 0, stream>>>(bin_cursor, bin_buf, cursor, col, N_NODES);
    gather_kernel<128, true><<<NODE_BLOCKS, 256, 0, stream>>>(
        (const half4*)H, as_, ad_, cursor, col, b0, B0, N_NODES);

    // ---- layer 1: B0 -> B0 (relu) ----
    mfma_gemm_kernel<128><<<GEMM_BLOCKS, 256, 0, stream>>>(B0, Wt1, as1, ad1, H, as_, ad_, N_NODES);
    gather_kernel<128, true><<<NODE_BLOCKS, 256, 0, stream>>>(
        (const half4*)H, as_, ad_, cursor, col, b1, B0, N_NODES);

    // ---- layer 2: B0 -> B0 (64-wide, no relu) ----
    mfma_gemm_kernel<64><<<GEMM_BLOCKS, 256, 0, stream>>>(B0, Wt2, as2, ad2, H, as_, ad_, N_NODES);
    gather_kernel<64, false><<<NODE_BLOCKS, 256, 0, stream>>>(
        (const half4*)H, as_, ad_, cursor, col, b2, B0, N_NODES);

    // ---- pool ----
    hipMemsetAsync(d_out, 0, (size_t)out_size * sizeof(float), stream);
    pool_kernel<<<(N_NODES + 127) / 128, 256, 0, stream>>>(B0, batch, (float*)d_out, N_NODES);
}

// Round 6
// 250.966 us; speedup vs baseline: 1.6133x; 1.0663x over previous
//
#include <hip/hip_runtime.h>
#include <hip/hip_fp16.h>
#include <math.h>

#define N_NODES 50000
#define N_EDGES 800000
#define N_GRAPHS 64
#define NEG_SLOPE 0.2f
#define SLOTS 64        // bucket capacity; P(in-degree>64) ~ 1e-20 for Poisson(16)

// ---- multisplit fill parameters ----
#define BIN_NODES 256                   // nodes per dst-range bin
#define NBINS 196                       // ceil(50000/256)
#define CAP 6144                        // u32 slots per bin (mean 4082, sigma ~64)
#define P1_BLOCKS 192                   // pass-1 blocks fused ahead of gemm0
#define BATCH 2048                      // edges per block-batch (8 per thread)

typedef _Float16 f16x8 __attribute__((ext_vector_type(8)));
typedef float f32x4 __attribute__((ext_vector_type(4)));

__device__ __forceinline__ float leaky(float x) {
    return x > 0.f ? x : NEG_SLOPE * x;
}

// 16-byte chunk of 8 fp16 values (gather load/store granule)
struct __align__(16) half8 {
    __half2 h[4];
};

// ------- prep: W -> MFMA lane-major fp16 fragments; zero bin_cursor + d_out -------
// Wt layout: [kt][ct][lane][8] halves; lane l supplies B[k=kt*32+(l>>4)*8+b][c=ct*16+(l&15)].
__global__ __launch_bounds__(256) void prep_kernel(const float* __restrict__ W0,
                                                   const float* __restrict__ W1,
                                                   const float* __restrict__ W2,
                                                   _Float16* __restrict__ Wt0,
                                                   _Float16* __restrict__ Wt1,
                                                   _Float16* __restrict__ Wt2,
                                                   unsigned int* __restrict__ bin_cursor,
                                                   float* __restrict__ dout, int osz) {
    const int t = blockIdx.x * 256 + threadIdx.x;
    if (t < NBINS) bin_cursor[t] = 0;
    if (t < osz) dout[t] = 0.f;  // replaces the separate hipMemsetAsync dispatch
    const float* W;
    _Float16* Wt;
    int g, CTl, DOUTl;
    if (t < 2048) { W = W0; Wt = Wt0; g = t; CTl = 8; DOUTl = 128; }
    else if (t < 4096) { W = W1; Wt = Wt1; g = t - 2048; CTl = 8; DOUTl = 128; }
    else if (t < 5120) { W = W2; Wt = Wt2; g = t - 4096; CTl = 4; DOUTl = 64; }
    else return;
    const int kt = g / (CTl * 64);
    const int rem = g % (CTl * 64);
    const int ct = rem / 64;
    const int lane = rem % 64;
    const int kbase = kt * 32 + (lane >> 4) * 8;
    const int c = ct * 16 + (lane & 15);
#pragma unroll
    for (int b = 0; b < 8; ++b)
        Wt[(size_t)g * 8 + b] = (_Float16)W[(size_t)(kbase + b) * DOUTl + c];
}

// ------- MFMA GEMM body: H(fp16) = X @ W; as_ = h@a_src, ad_ = h@a_dst -------
// Block = 64 rows x DOUT cols, 4 waves x 16 rows. K=128 via 4x mfma_f32_16x16x32_f16.
// xs: 64x128 fp16 in LDS, 16B-chunk XOR swizzle (q ^ (row&15)) -> conflict-free A reads.
// XT = float (layer 0 input) or _Float16 (X written fp16 by the previous gather).
template <int DOUT, typename XT>
__device__ __forceinline__ void mfma_gemm_body(const XT* __restrict__ X,
                                               const _Float16* __restrict__ Wt,
                                               const float* __restrict__ a_src,
                                               const float* __restrict__ a_dst,
                                               _Float16* __restrict__ H,
                                               float* __restrict__ as_,
                                               float* __restrict__ ad_, int N, int bid,
                                               _Float16* xs) {
    constexpr int CT = DOUT / 16;
    const int tid = threadIdx.x;
    const int n0 = bid * 64;

    if constexpr (sizeof(XT) == 4) {
        const float4* X4 = reinterpret_cast<const float4*>(X);
        for (int idx = tid; idx < 64 * 16; idx += 256) {
            const int r = idx >> 4, q = idx & 15;
            const int n = n0 + r;
            float4 v0 = make_float4(0.f, 0.f, 0.f, 0.f), v1 = v0;
            if (n < N) {
                v0 = X4[(size_t)n * 32 + 2 * q];
                v1 = X4[(size_t)n * 32 + 2 * q + 1];
            }
            f16x8 hv;
            hv[0] = (_Float16)v0.x; hv[1] = (_Float16)v0.y;
            hv[2] = (_Float16)v0.z; hv[3] = (_Float16)v0.w;
            hv[4] = (_Float16)v1.x; hv[5] = (_Float16)v1.y;
            hv[6] = (_Float16)v1.z; hv[7] = (_Float16)v1.w;
            *reinterpret_cast<f16x8*>(&xs[r * 128 + ((q ^ (r & 15)) << 3)]) = hv;
        }
    } else {
        const f16x8* X8 = reinterpret_cast<const f16x8*>(X);
        for (int idx = tid; idx < 64 * 16; idx += 256) {
            const int r = idx >> 4, q = idx & 15;
            const int n = n0 + r;
            f16x8 hv = {};
            if (n < N) hv = X8[(size_t)n * 16 + q];
            *reinterpret_cast<f16x8*>(&xs[r * 128 + ((q ^ (r & 15)) << 3)]) = hv;
        }
    }
    __syncthreads();

    const int wave = tid >> 6, lane = tid & 63;
    const int colb = lane & 15;   // col within 16-tile; also A-row within wave tile
    const int kg = lane >> 4;     // k-group 0..3 (A); row-group (C/D)
    const int arow = wave * 16 + colb;

    f32x4 acc[CT];
#pragma unroll
    for (int ct = 0; ct < CT; ++ct) {
        acc[ct][0] = 0.f; acc[ct][1] = 0.f; acc[ct][2] = 0.f; acc[ct][3] = 0.f;
    }
    const f16x8* Wt8 = reinterpret_cast<const f16x8*>(Wt);
#pragma unroll
    for (int kt = 0; kt < 4; ++kt) {
        f16x8 A = *reinterpret_cast<const f16x8*>(
            &xs[arow * 128 + (((kt * 4 + kg) ^ (arow & 15)) << 3)]);
#pragma unroll
        for (int ct = 0; ct < CT; ++ct) {
            f16x8 B = Wt8[(kt * CT + ct) * 64 + lane];
            acc[ct] = __builtin_amdgcn_mfma_f32_16x16x32_f16(A, B, acc[ct], 0, 0, 0);
        }
    }

    // epilogue: H store (fp16) + alpha partials from f32 accs
    float ps[4] = {0.f, 0.f, 0.f, 0.f}, pd[4] = {0.f, 0.f, 0.f, 0.f};
#pragma unroll
    for (int ct = 0; ct < CT; ++ct) {
        const int col = ct * 16 + colb;
        const float asv = a_src[col];
        const float adv = a_dst[col];
#pragma unroll
        for (int r = 0; r < 4; ++r) {
            const float d = acc[ct][r];
            ps[r] += d * asv;
            pd[r] += d * adv;
            const int row = n0 + wave * 16 + kg * 4 + r;
            if (row < N) H[(size_t)row * DOUT + col] = (_Float16)d;
        }
    }
#pragma unroll
    for (int off = 1; off < 16; off <<= 1) {
#pragma unroll
        for (int r = 0; r < 4; ++r) {
            ps[r] += __shfl_xor(ps[r], off, 64);
            pd[r] += __shfl_xor(pd[r], off, 64);
        }
    }
    if (colb == 0) {
#pragma unroll
        for (int r = 0; r < 4; ++r) {
            const int row = n0 + wave * 16 + kg * 4 + r;
            if (row < N) {
                as_[row] = ps[r];
                ad_[row] = pd[r];
            }
        }
    }
}

template <int DOUT, typename XT>
__global__ __launch_bounds__(256) void mfma_gemm_kernel(const XT* __restrict__ X,
                                                        const _Float16* __restrict__ Wt,
                                                        const float* __restrict__ a_src,
                                                        const float* __restrict__ a_dst,
                                                        _Float16* __restrict__ H,
                                                        float* __restrict__ as_,
                                                        float* __restrict__ ad_, int N) {
    __shared__ __align__(16) _Float16 xs[64 * 128];
    mfma_gemm_body<DOUT, XT>(X, Wt, a_src, a_dst, H, as_, ad_, N, blockIdx.x, xs);
}

// ------- pass 1: multisplit edges into 196 dst-range bins (packed u32 = d<<16|s) -------
struct P1Smem {
    unsigned int stage[BATCH];
    int hist[NBINS];
    int off[NBINS];
    unsigned int gbase[NBINS];
    int total;
};

__device__ __forceinline__ void fill_pass1(const int* __restrict__ src,
                                           const int* __restrict__ dst,
                                           unsigned int* __restrict__ bin_cursor,
                                           unsigned int* __restrict__ bin_buf,
                                           int E, int bid, void* smem_raw) {
    P1Smem& S = *reinterpret_cast<P1Smem*>(smem_raw);
    const int tid = threadIdx.x;
    const int nbatch = (E + BATCH - 1) / BATCH;
    for (int b = bid; b < nbatch; b += P1_BLOCKS) {
        __syncthreads();  // protect stage/hist reuse across batches
        for (int i = tid; i < NBINS; i += 256) S.hist[i] = 0;
        const int e0 = b * BATCH;
        unsigned int pk[8];
        int rk[8];
        bool ok[8];
#pragma unroll
        for (int k = 0; k < 8; ++k) {
            int e = e0 + tid + k * 256;
            ok[k] = (e < E);
            int d = ok[k] ? dst[e] : 0;
            int s = ok[k] ? src[e] : 0;
            pk[k] = ((unsigned)d << 16) | (unsigned)s;
            rk[k] = 0;
        }
        __syncthreads();
#pragma unroll
        for (int k = 0; k < 8; ++k)
            if (ok[k]) rk[k] = atomicAdd(&S.hist[pk[k] >> 24], 1);
        __syncthreads();
        // parallel Hillis-Steele inclusive scan (replaces tid0 serial 196-iter scan)
        for (int i = tid; i < NBINS; i += 256) S.off[i] = S.hist[i];
        __syncthreads();
#pragma unroll
        for (int d = 1; d < 256; d <<= 1) {
            int v = 0;
            if (tid < NBINS && tid >= d) v = S.off[tid - d];
            __syncthreads();
            if (tid < NBINS) S.off[tid] += v;
            __syncthreads();
        }
        if (tid == NBINS - 1) S.total = S.off[NBINS - 1];
        __syncthreads();
        if (tid < NBINS) S.off[tid] -= S.hist[tid];  // exclusive
        __syncthreads();
        if (tid < NBINS && S.hist[tid] > 0)
            S.gbase[tid] = atomicAdd(&bin_cursor[tid], (unsigned)S.hist[tid]);
#pragma unroll
        for (int k = 0; k < 8; ++k)
            if (ok[k]) S.stage[S.off[pk[k] >> 24] + rk[k]] = pk[k];
        __syncthreads();
        const int tot = S.total;
        for (int i = tid; i < tot; i += 256) {
            unsigned int v = S.stage[i];
            int bn = v >> 24;
            unsigned int p = S.gbase[bn] + (unsigned)(i - S.off[bn]);
            if (p < CAP) bin_buf[(size_t)bn * CAP + p] = v;
        }
    }
}

// ------- fused layer-0 MFMA GEMM + pass-1 (independent dataflow -> overlap) -------
__global__ __launch_bounds__(256) void gemm0_fill_kernel(
    const float* __restrict__ X, const _Float16* __restrict__ Wt0,
    const float* __restrict__ a_src, const float* __restrict__ a_dst,
    _Float16* __restrict__ H, float* __restrict__ as_, float* __restrict__ ad_, int N,
    const int* __restrict__ src, const int* __restrict__ dst,
    unsigned int* __restrict__ bin_cursor, unsigned int* __restrict__ bin_buf, int E) {
    __shared__ __align__(16) unsigned char smem[16384];  // union: P1Smem (10.5KB) / xs (16KB)
    if (blockIdx.x < P1_BLOCKS) {
        fill_pass1(src, dst, bin_cursor, bin_buf, E, blockIdx.x, smem);
        return;
    }
    mfma_gemm_body<128, float>(X, Wt0, a_src, a_dst, H, as_, ad_, N, blockIdx.x - P1_BLOCKS,
                               reinterpret_cast<_Float16*>(smem));
}

// ------- pass 2: per-bin bucket build in LDS, coalesced writeback -------
__global__ __launch_bounds__(256) void fill_pass2(const unsigned int* __restrict__ bin_cursor,
                                                  const unsigned int* __restrict__ bin_buf,
                                                  int* __restrict__ cursor,
                                                  unsigned short* __restrict__ col, int N) {
    __shared__ unsigned short bk[BIN_NODES][SLOTS];  // 32KB
    __shared__ int cnt[BIN_NODES];                   // 1KB
    const int b = blockIdx.x;
    const int tid = threadIdx.x;
    const int base = b * BIN_NODES;
    const int nn = min(BIN_NODES, N - base);
    if (nn <= 0) return;
    cnt[tid] = 0;
    __syncthreads();
    const int ec = min((int)bin_cursor[b], CAP);
    for (int i = tid; i < ec; i += 256) {
        unsigned int v = bin_buf[(size_t)b * CAP + i];
        int d = (int)(v >> 16) - base;  // in [0, BIN_NODES)
        int p = atomicAdd(&cnt[d], 1);
        if (p < SLOTS) bk[d][p] = (unsigned short)(v & 0xFFFFu);
    }
    __syncthreads();
    unsigned int* col32 = reinterpret_cast<unsigned int*>(col);
    const unsigned int* lds32 = reinterpret_cast<const unsigned int*>(&bk[0][0]);
    const int words = nn * (SLOTS / 2);
    for (int i = tid; i < words; i += 256)
        col32[(size_t)base * (SLOTS / 2) + i] = lds32[i];
    if (tid < nn) cursor[base + tid] = cnt[tid];
}

// ------- fused softmax + gather per dst node (wave per node, no max pass) -------
// H fp16; 16B loads (NCH = DOUT/8 lanes per edge). POOL=false: fp16 OUT + relu
// (feeds next gemm). POOL=true (layer 2): block-reduce 4 rows in LDS and
// atomicAdd into d_out (pool_kernel + its 25MB round-trip + memset eliminated).
template <int DOUT, bool POOL>
__global__ __launch_bounds__(256) void gather_kernel(const half8* __restrict__ H8,
                                                     const float* __restrict__ as_,
                                                     const float* __restrict__ ad_,
                                                     const int* __restrict__ cursor,
                                                     const unsigned short* __restrict__ col,
                                                     const float* __restrict__ bias,
                                                     half8* __restrict__ OUT,
                                                     const int* __restrict__ batch,
                                                     float* __restrict__ pool_out, int N) {
    constexpr int NCH = DOUT / 8;   // lanes per edge: 16 or 8
    constexpr int SUBS = 64 / NCH;  // subgroups: 4 or 8
    __shared__ float pbuf[4][64];
    __shared__ int pg[4];
    const int wv = threadIdx.x >> 6;
    const int node = blockIdx.x * 4 + wv;
    if (!POOL && node >= N) return;  // N%4==0: never fires, kept for safety
    const int l = threadIdx.x & 63;
    const int ch = l & (NCH - 1);
    const int sub = l / NCH;

    const float adn = ad_[node];
    const float sl = leaky(as_[node] + adn);
    const int rs = node << 6;
    const int re = rs + min(cursor[node], SLOTS);

    float acc[8] = {};
    float dsum = 0.f;

    int i = rs + sub;
    for (; i + 3 * SUBS < re; i += 4 * SUBS) {
        int s[4];
        float a[4];
        half8 h[4];
#pragma unroll
        for (int u = 0; u < 4; ++u) s[u] = col[i + u * SUBS];
#pragma unroll
        for (int u = 0; u < 4; ++u) a[u] = as_[s[u]];
#pragma unroll
        for (int u = 0; u < 4; ++u) h[u] = H8[(size_t)s[u] * NCH + ch];
#pragma unroll
        for (int u = 0; u < 4; ++u) {
            float ee = __expf(leaky(a[u] + adn));
#pragma unroll
            for (int j = 0; j < 4; ++j) {
                float2 f = __half22float2(h[u].h[j]);
                acc[2 * j] += ee * f.x;
                acc[2 * j + 1] += ee * f.y;
            }
            dsum += ee;
        }
    }
    for (; i + SUBS < re; i += 2 * SUBS) {
        int s0 = col[i], s1 = col[i + SUBS];
        float a0 = as_[s0], a1 = as_[s1];
        half8 h0 = H8[(size_t)s0 * NCH + ch];
        half8 h1 = H8[(size_t)s1 * NCH + ch];
        float e0 = __expf(leaky(a0 + adn));
        float e1 = __expf(leaky(a1 + adn));
#pragma unroll
        for (int j = 0; j < 4; ++j) {
            float2 f0 = __half22float2(h0.h[j]);
            float2 f1 = __half22float2(h1.h[j]);
            acc[2 * j] += e0 * f0.x + e1 * f1.x;
            acc[2 * j + 1] += e0 * f0.y + e1 * f1.y;
        }
        dsum += e0 + e1;
    }
    if (i < re) {
        int s0 = col[i];
        float e0 = __expf(leaky(as_[s0] + adn));
        half8 h0 = H8[(size_t)s0 * NCH + ch];
#pragma unroll
        for (int j = 0; j < 4; ++j) {
            float2 f = __half22float2(h0.h[j]);
            acc[2 * j] += e0 * f.x;
            acc[2 * j + 1] += e0 * f.y;
        }
        dsum += e0;
    }

    // dsum identical across a subgroup's NCH lanes; combine subgroups only
#pragma unroll
    for (int off = 32; off >= NCH; off >>= 1)
        dsum += __shfl_xor(dsum, off, 64);
#pragma unroll
    for (int off = 32; off >= NCH; off >>= 1) {
#pragma unroll
        for (int j = 0; j < 8; ++j)
            acc[j] += __shfl_down(acc[j], off, 64);
    }

    if (l < NCH) {
        const float e_self = __expf(sl);
        half8 h = H8[(size_t)node * NCH + ch];
        const float inv_pre = dsum + e_self;
        const float inv = 1.f / inv_pre;
        const float4* b4 = reinterpret_cast<const float4*>(bias);
        const float4 ba = b4[2 * ch], bb = b4[2 * ch + 1];
        const float bj[8] = {ba.x, ba.y, ba.z, ba.w, bb.x, bb.y, bb.z, bb.w};
        float r[8];
#pragma unroll
        for (int j = 0; j < 4; ++j) {
            float2 f = __half22float2(h.h[j]);
            acc[2 * j] += e_self * f.x;
            acc[2 * j + 1] += e_self * f.y;
        }
#pragma unroll
        for (int j = 0; j < 8; ++j) {
            r[j] = acc[j] * inv + bj[j];
            if (!POOL) r[j] = fmaxf(r[j], 0.f);  // relu on layers 0/1 only
        }
        if (POOL) {
#pragma unroll
            for (int j = 0; j < 8; ++j) pbuf[wv][ch * 8 + j] = r[j];
        } else {
            half8 o;
#pragma unroll
            for (int j = 0; j < 4; ++j)
                o.h[j] = __floats2half2_rn(r[2 * j], r[2 * j + 1]);
            OUT[(size_t)node * NCH + ch] = o;
        }
    }
    if (POOL) {
        if (l == 0) pg[wv] = batch[node];
        __syncthreads();
        if (threadIdx.x < 64) {
            const int c = threadIdx.x;
            const int g0 = pg[0], g3 = pg[3];
            if (g0 == g3) {  // batch sorted: g0==g3 => all four equal (common case)
                atomicAdd(&pool_out[g0 * 64 + c],
                          pbuf[0][c] + pbuf[1][c] + pbuf[2][c] + pbuf[3][c]);
            } else {
#pragma unroll
                for (int w = 0; w < 4; ++w)
                    atomicAdd(&pool_out[pg[w] * 64 + c], pbuf[w][c]);
            }
        }
    }
}

extern "C" void kernel_launch(void* const* d_in, const int* in_sizes, int n_in,
                              void* d_out, int out_size, void* d_ws, size_t ws_size,
                              hipStream_t stream) {
    const float* x = (const float*)d_in[0];
    const int* edge_index = (const int*)d_in[1];
    const int* batch = (const int*)d_in[2];
    const float* W0 = (const float*)d_in[3];
    const float* as0 = (const float*)d_in[4];
    const float* ad0 = (const float*)d_in[5];
    const float* b0 = (const float*)d_in[6];
    const float* W1 = (const float*)d_in[7];
    const float* as1 = (const float*)d_in[8];
    const float* ad1 = (const float*)d_in[9];
    const float* b1 = (const float*)d_in[10];
    const float* W2 = (const float*)d_in[11];
    const float* as2 = (const float*)d_in[12];
    const float* ad2 = (const float*)d_in[13];
    const float* b2 = (const float*)d_in[14];

    const int* e_src = edge_index;            // row 0
    const int* e_dst = edge_index + N_EDGES;  // row 1

    // workspace layout (byte-based; every region 16B-aligned)
    char* p = (char*)d_ws;
    _Float16* X16 = (_Float16*)p;     p += (size_t)N_NODES * 128 * 2;   // 12.8MB fp16 intermediate
    _Float16* H = (_Float16*)p;       p += (size_t)N_NODES * 128 * 2;   // 12.8MB
    float* as_ = (float*)p;           p += (size_t)N_NODES * 4;
    float* ad_ = (float*)p;           p += (size_t)N_NODES * 4;
    int* cursor = (int*)p;            p += (size_t)N_NODES * 4;
    unsigned short* col = (unsigned short*)p; p += (size_t)N_NODES * SLOTS * 2;  // 6.4MB
    unsigned int* bin_cursor = (unsigned int*)p; p += (size_t)((NBINS + 3) & ~3) * 4;
    unsigned int* bin_buf = (unsigned int*)p; p += (size_t)NBINS * CAP * 4;      // 4.8MB
    _Float16* Wt0 = (_Float16*)p;     p += (size_t)16384 * 2;
    _Float16* Wt1 = (_Float16*)p;     p += (size_t)16384 * 2;
    _Float16* Wt2 = (_Float16*)p;     p += (size_t)8192 * 2;

    const int NODE_BLOCKS = (N_NODES + 3) / 4;
    const int GEMM_BLOCKS = (N_NODES + 63) / 64;

    // ---- prep: W fragments + bin_cursor zero + d_out zero ----
    prep_kernel<<<20, 256, 0, stream>>>(W0, W1, W2, Wt0, Wt1, Wt2, bin_cursor,
                                        (float*)d_out, out_size);

    // ---- layer 0 MFMA gemm fused with fill pass-1 (independent -> overlap) ----
    gemm0_fill_kernel<<<P1_BLOCKS + GEMM_BLOCKS, 256, 0, stream>>>(
        x, Wt0, as0, ad0, H, as_, ad_, N_NODES, e_src, e_dst, bin_cursor, bin_buf, N_EDGES);
    fill_pass2<<<NBINS, 256, 0, stream>>>(bin_cursor, bin_buf, cursor, col, N_NODES);
    gather_kernel<128, false><<<NODE_BLOCKS, 256, 0, stream>>>(
        (const half8*)H, as_, ad_, cursor, col, b0, (half8*)X16, batch, nullptr, N_NODES);

    // ---- layer 1: X16 -> H (relu inside gather) ----
    mfma_gemm_kernel<128, _Float16><<<GEMM_BLOCKS, 256, 0, stream>>>(
        X16, Wt1, as1, ad1, H, as_, ad_, N_NODES);
    gather_kernel<128, false><<<NODE_BLOCKS, 256, 0, stream>>>(
        (const half8*)H, as_, ad_, cursor, col, b1, (half8*)X16, batch, nullptr, N_NODES);

    // ---- layer 2: X16 -> H (64-wide), gather fused with global add pool ----
    mfma_gemm_kernel<64, _Float16><<<GEMM_BLOCKS, 256, 0, stream>>>(
        X16, Wt2, as2, ad2, H, as_, ad_, N_NODES);
    gather_kernel<64, true><<<NODE_BLOCKS, 256, 0, stream>>>(
        (const half8*)H, as_, ad_, cursor, col, b2, nullptr, batch, (float*)d_out, N_NODES);
}